// Round 5
// baseline (942.084 us; speedup 1.0000x reference)
//
#include <hip/hip_runtime.h>
#include <hip/hip_bf16.h>

#define DEV static __device__ __forceinline__

typedef short short8 __attribute__((ext_vector_type(8)));
typedef short short4v __attribute__((ext_vector_type(4)));
typedef float f32x4 __attribute__((ext_vector_type(4)));

#define NB 512
#define SL 256
#define ED 300
#define HD 200
#define EP 320   // padded embed stride
#define HP 224   // padded hidden stride
#define TSP 232  // LDS layer-1 output tile stride
#define PAD 40
#define GSTR 53248   // per-(b,side) Gt size in shorts: 208*256

#define MFMA(a,b,c) __builtin_amdgcn_mfma_f32_16x16x32_bf16(a,b,c,0,0,0)

DEV short f2b(float f){ __hip_bfloat16 h = __float2bfloat16(f); short s; __builtin_memcpy(&s,&h,2); return s; }

// zero-guarded weight-row loader (rows >= 208 read as zero)
DEV short8 ldg_row(const short* __restrict__ Wt, int n, size_t stride, int off){
  if (n < 208) return *(const short8*)&Wt[(size_t)n*stride + off];
  short8 z = {0,0,0,0,0,0,0,0};
  return z;
}

// ---------- one-time conversions ----------
__global__ __launch_bounds__(256) void conv_emb(const float* __restrict__ src, short* __restrict__ dst){
  size_t g = (size_t)blockIdx.x*256 + threadIdx.x;
  if (g >= (size_t)50000*EP) return;
  int row = (int)(g/EP), k = (int)(g%EP);
  dst[g] = (k<ED) ? f2b(src[(size_t)row*ED + k]) : (short)0;
}
// Wt[n][k] (208 x KP) <- W[k][n] (Kreal x 200), zero padded
__global__ __launch_bounds__(256) void convT_plain(const float* __restrict__ W, short* __restrict__ Wt,
                                                   int Kreal, int KP){
  int g = blockIdx.x*256 + threadIdx.x;
  if (g >= 208*KP) return;
  int n = g/KP, k = g%KP;
  float v = (n<HD && k<Kreal) ? W[(size_t)k*HD + n] : 0.f;
  Wt[g] = f2b(v);
}

// ---------- fused 2-layer attend MLP ----------
// M=64 rows/block; 4 waves = 2x2 (row-half x col-half). Layer-1 A loaded per-lane
// direct from global (no LDS round trip); B staged once (224 rows, >=208 zero).
__global__ __launch_bounds__(256) void mlp2(
    const short* __restrict__ embb,
    const int* __restrict__ idxA, const int* __restrict__ idxB,
    const short* __restrict__ W1t, const float* __restrict__ b1,
    const short* __restrict__ W2t, const float* __restrict__ b2,
    short* __restrict__ OutA, short* __restrict__ OutB)
{
  __shared__ __align__(16) short U[64*TSP];      // layer-1 output only
  __shared__ __align__(16) short Bs[224*PAD];
  __shared__ int IdxS[64];
  const int tid=threadIdx.x, lane=tid&63, w=tid>>6, quad=lane>>4, ln=lane&15;
  const int rt=w&1, ch=w>>1;
  const int half = gridDim.x>>1;
  const int side = (blockIdx.x >= half) ? 1 : 0;
  const int row0 = (blockIdx.x - side*half)*64;
  const int* idx = side ? idxB : idxA;
  if (tid < 64) IdxS[tid] = idx[row0+tid];
  __syncthreads();

  f32x4 acc0[7], acc1[7];
  #pragma unroll
  for (int t=0;t<7;t++){ acc0[t]=(f32x4){0,0,0,0}; acc1[t]=(f32x4){0,0,0,0}; }
  const int r_ = tid>>2, c_ = tid&3;
  const short* aP0 = &embb[(size_t)IdxS[rt*32+ln]*EP];
  const short* aP1 = &embb[(size_t)IdxS[rt*32+16+ln]*EP];

  short8 bR0, bR1, bR2, bR3, aC0, aC1, aN0, aN1;
  bR0 = *(const short8*)&W1t[(size_t)r_*EP + c_*8];
  bR1 = *(const short8*)&W1t[(size_t)(64+r_)*EP + c_*8];
  bR2 = *(const short8*)&W1t[(size_t)(128+r_)*EP + c_*8];
  if (r_<32) bR3 = ldg_row(W1t, 192+r_, EP, c_*8);
  aC0 = *(const short8*)&aP0[quad*8];
  aC1 = *(const short8*)&aP1[quad*8];
  aN0 = *(const short8*)&aP0[32 + quad*8];
  aN1 = *(const short8*)&aP1[32 + quad*8];

  // ---- layer 1 (K=320, 10 steps) ----
  for (int ks=0; ks<10; ks++){
    __syncthreads();
    *(short8*)&Bs[r_*PAD + c_*8] = bR0;
    *(short8*)&Bs[(64+r_)*PAD + c_*8] = bR1;
    *(short8*)&Bs[(128+r_)*PAD + c_*8] = bR2;
    if (r_<32) *(short8*)&Bs[(192+r_)*PAD + c_*8] = bR3;
    __syncthreads();
    if (ks < 9){
      const int k0 = (ks+1)*32;
      bR0 = *(const short8*)&W1t[(size_t)r_*EP + k0 + c_*8];
      bR1 = *(const short8*)&W1t[(size_t)(64+r_)*EP + k0 + c_*8];
      bR2 = *(const short8*)&W1t[(size_t)(128+r_)*EP + k0 + c_*8];
      if (r_<32) bR3 = ldg_row(W1t, 192+r_, EP, k0 + c_*8);
    }
    short8 a0 = aC0, a1 = aC1;
    aC0 = aN0; aC1 = aN1;
    if (ks+2 < 10){
      aN0 = *(const short8*)&aP0[(ks+2)*32 + quad*8];
      aN1 = *(const short8*)&aP1[(ks+2)*32 + quad*8];
    }
    #pragma unroll
    for (int tt=0; tt<7; tt++){
      short8 bb = *(const short8*)&Bs[(ch*112 + tt*16 + ln)*PAD + quad*8];
      acc0[tt] = MFMA(a0, bb, acc0[tt]);
      acc1[tt] = MFMA(a1, bb, acc1[tt]);
    }
  }
  // layer-1 epilogue -> U (cols >= HD written zero; covers 200..223 pad)
  #pragma unroll
  for (int tt=0; tt<7; tt++){
    int col = (ch*7+tt)*16+ln;
    float bv = (col<HD) ? b1[col] : 0.f;
    #pragma unroll
    for (int r=0;r<4;r++){
      int rl = rt*32 + quad*4 + r;
      U[(rl   )*TSP + col] = f2b((col<HD) ? fmaxf(acc0[tt][r]+bv, 0.f) : 0.f);
      U[(rl+16)*TSP + col] = f2b((col<HD) ? fmaxf(acc1[tt][r]+bv, 0.f) : 0.f);
    }
    acc0[tt]=(f32x4){0,0,0,0}; acc1[tt]=(f32x4){0,0,0,0};
  }

  // ---- layer 2 (K=224, 7 steps) ----
  bR0 = *(const short8*)&W2t[(size_t)r_*HP + c_*8];
  bR1 = *(const short8*)&W2t[(size_t)(64+r_)*HP + c_*8];
  bR2 = *(const short8*)&W2t[(size_t)(128+r_)*HP + c_*8];
  if (r_<32) bR3 = ldg_row(W2t, 192+r_, HP, c_*8);
  for (int ks=0; ks<7; ks++){
    __syncthreads();   // first iter: covers epilogue U writes + last layer-1 Bs reads
    *(short8*)&Bs[r_*PAD + c_*8] = bR0;
    *(short8*)&Bs[(64+r_)*PAD + c_*8] = bR1;
    *(short8*)&Bs[(128+r_)*PAD + c_*8] = bR2;
    if (r_<32) *(short8*)&Bs[(192+r_)*PAD + c_*8] = bR3;
    __syncthreads();
    if (ks < 6){
      const int k0 = (ks+1)*32;
      bR0 = *(const short8*)&W2t[(size_t)r_*HP + k0 + c_*8];
      bR1 = *(const short8*)&W2t[(size_t)(64+r_)*HP + k0 + c_*8];
      bR2 = *(const short8*)&W2t[(size_t)(128+r_)*HP + k0 + c_*8];
      if (r_<32) bR3 = ldg_row(W2t, 192+r_, HP, k0 + c_*8);
    }
    short8 a0 = *(const short8*)&U[(rt*32+ln)*TSP + ks*32 + quad*8];
    short8 a1 = *(const short8*)&U[(rt*32+16+ln)*TSP + ks*32 + quad*8];
    #pragma unroll
    for (int tt=0; tt<7; tt++){
      short8 bb = *(const short8*)&Bs[(ch*112 + tt*16 + ln)*PAD + quad*8];
      acc0[tt] = MFMA(a0, bb, acc0[tt]);
      acc1[tt] = MFMA(a1, bb, acc1[tt]);
    }
  }
  short* Out = side ? OutB : OutA;
  #pragma unroll
  for (int tt=0; tt<7; tt++){
    int col = (ch*7+tt)*16+ln;
    float bv = (col<HD) ? b2[col] : 0.f;
    #pragma unroll
    for (int r=0;r<4;r++){
      int rl = rt*32 + quad*4 + r;
      Out[(size_t)(row0+rl   )*HP + col] = f2b((col<HD) ? fmaxf(acc0[tt][r]+bv, 0.f) : 0.f);
      Out[(size_t)(row0+rl+16)*HP + col] = f2b((col<HD) ? fmaxf(acc1[tt][r]+bv, 0.f) : 0.f);
    }
  }
}

// ---------- scores + fused row/col max (e >= 0 since h >= 0) ----------
__global__ __launch_bounds__(256) void scores_gemm(
    const short* __restrict__ h1, const short* __restrict__ h2, float* __restrict__ e,
    unsigned* __restrict__ RmU, unsigned* __restrict__ CmU)
{
  __shared__ __align__(16) short As[64*PAD];
  __shared__ __align__(16) short Bs[64*PAD];
  const int b = blockIdx.z;
  const int i0 = blockIdx.x*64, j0 = blockIdx.y*64;
  const int tid=threadIdx.x, lane=tid&63, w=tid>>6, quad=lane>>4, ln=lane&15;
  const int r_ = tid>>2, c_ = tid&3;
  f32x4 acc[4];
  #pragma unroll
  for (int t=0;t<4;t++) acc[t]=(f32x4){0.f,0.f,0.f,0.f};
  const short* Arow = &h1[((size_t)b*SL + i0 + r_)*HP + c_*8];
  const short* Brow = &h2[((size_t)b*SL + j0 + r_)*HP + c_*8];
  short8 aR = *(const short8*)Arow;
  short8 bR = *(const short8*)Brow;
  for (int ks=0; ks<7; ks++){
    __syncthreads();
    *(short8*)&As[r_*PAD + c_*8] = aR;
    *(short8*)&Bs[r_*PAD + c_*8] = bR;
    __syncthreads();
    if (ks < 6){
      aR = *(const short8*)(Arow + (ks+1)*32);
      bR = *(const short8*)(Brow + (ks+1)*32);
    }
    short8 a = *(const short8*)&As[(w*16+ln)*PAD + quad*8];
    #pragma unroll
    for (int t=0;t<4;t++){
      short8 bb = *(const short8*)&Bs[(t*16+ln)*PAD + quad*8];
      acc[t] = MFMA(a, bb, acc[t]);
    }
  }
  #pragma unroll
  for (int t=0;t<4;t++){
    int j = j0 + t*16 + ln;
    #pragma unroll
    for (int r=0;r<4;r++){
      int i = i0 + w*16 + quad*4 + r;
      e[(size_t)b*SL*SL + (size_t)i*SL + j] = acc[t][r];
    }
  }
  // row maxes (over j): reduce over ln within quad-group
  #pragma unroll
  for (int r=0;r<4;r++){
    float m = fmaxf(fmaxf(acc[0][r],acc[1][r]), fmaxf(acc[2][r],acc[3][r]));
    m=fmaxf(m,__shfl_xor(m,1)); m=fmaxf(m,__shfl_xor(m,2));
    m=fmaxf(m,__shfl_xor(m,4)); m=fmaxf(m,__shfl_xor(m,8));
    if (ln==0) atomicMax(&RmU[b*SL + i0 + w*16 + quad*4 + r], __float_as_uint(m));
  }
  // col maxes (over i): reduce over quad
  #pragma unroll
  for (int t=0;t<4;t++){
    float m = fmaxf(fmaxf(acc[t][0],acc[t][1]), fmaxf(acc[t][2],acc[t][3]));
    m=fmaxf(m,__shfl_xor(m,16)); m=fmaxf(m,__shfl_xor(m,32));
    if (quad==0) atomicMax(&CmU[b*SL + j0 + t*16 + ln], __float_as_uint(m));
  }
}

// ---------- P weights, normalized + masked + row-zeroed ----------
__global__ __launch_bounds__(256) void pwrite_k(
    const float* __restrict__ e, const unsigned* __restrict__ RmU, const unsigned* __restrict__ CmU,
    const int* __restrict__ len1, const int* __restrict__ len2,
    short* __restrict__ Pa, short* __restrict__ Pb)
{
  const int b = blockIdx.z, s = blockIdx.x, ori = blockIdx.y;
  const float* eb = e + (size_t)b*SL*SL;
  const int tid = threadIdx.x, lane = tid&63, w = tid>>6;
  if (ori == 0){
    const int l1 = len1[b], l2 = len2[b];
    if (s*64 >= l1) return;          // rows >= l1 are stale; masked out downstream
    for (int t=0;t<16;t++){
      int i = s*64 + w*16 + t;
      if (i >= l1) break;
      float cm = __uint_as_float(CmU[b*SL+i]);
      float4 v = ((const float4*)(eb + (size_t)i*SL))[lane];
      int c0 = lane*4;
      float e0 = (c0+0<l2) ? __expf(fminf(v.x-cm,85.f)) : 0.f;
      float e1 = (c0+1<l2) ? __expf(fminf(v.y-cm,85.f)) : 0.f;
      float e2 = (c0+2<l2) ? __expf(fminf(v.z-cm,85.f)) : 0.f;
      float e3 = (c0+3<l2) ? __expf(fminf(v.w-cm,85.f)) : 0.f;
      float ss = e0+e1+e2+e3;
      ss+=__shfl_xor(ss,1); ss+=__shfl_xor(ss,2); ss+=__shfl_xor(ss,4);
      ss+=__shfl_xor(ss,8); ss+=__shfl_xor(ss,16); ss+=__shfl_xor(ss,32);
      float inv = (ss>0.f) ? 1.f/ss : 0.f;
      short4v o; o[0]=f2b(e0*inv); o[1]=f2b(e1*inv); o[2]=f2b(e2*inv); o[3]=f2b(e3*inv);
      ((short4v*)(Pb + (size_t)b*SL*SL + (size_t)i*SL))[lane] = o;
    }
  } else {
    __shared__ float Part[4][64];
    __shared__ float SaInv[64];
    __shared__ float RmS[64];
    __shared__ float Tile[64][65];
    const int l1 = len1[b], l2 = len2[b];
    const int j0 = s*64;
    if (tid < 64) RmS[tid] = __uint_as_float(RmU[b*SL + j0 + tid]);
    __syncthreads();
    {
      float sum = 0.f;
      for (int i=w; i<l1; i+=4)
        sum += __expf(fminf(eb[(size_t)i*SL + j0 + lane] - RmS[lane], 85.f));
      Part[w][lane] = sum;
    }
    __syncthreads();
    if (w==0){
      float s_ = Part[0][lane]+Part[1][lane]+Part[2][lane]+Part[3][lane];
      SaInv[lane] = (s_>0.f && (j0+lane)<l2) ? 1.f/s_ : 0.f;  // j>=l2: zero row (mask2 on alphas)
    }
    __syncthreads();
    // only Pa columns < round_up_32(l1) are ever read by the K-trimmed mlp2c
    const int kmax = (l1+31)&~31;
    const int nti = (kmax+63)>>6;
    for (int ti=0; ti<nti; ti++){
      const int i0 = ti*64;
      #pragma unroll 4
      for (int it=0; it<16; it++){
        int il = it*4 + w;
        int i = i0 + il;
        float v = eb[(size_t)i*SL + j0 + lane];
        float p = (i<l1) ? __expf(fminf(v - RmS[lane],85.f))*SaInv[lane] : 0.f;
        Tile[il][lane] = p;
      }
      __syncthreads();
      {
        int jl = tid>>2, q = tid&3;
        short8 o1, o2;
        #pragma unroll
        for (int u=0;u<8;u++){
          o1[u] = f2b(Tile[q*16+u][jl]);
          o2[u] = f2b(Tile[q*16+8+u][jl]);
        }
        short* dst = Pa + (size_t)b*SL*SL + (size_t)(j0+jl)*SL + i0 + q*16;
        *(short8*)dst = o1;
        *(short8*)(dst+8) = o2;
      }
      __syncthreads();
    }
  }
}

// ---------- ggemm: Gt[n][k] = sum_d embb[idx[k]][d] * W1cb[n][d], stored transposed ----------
// 2x2 wave grid + direct-global A; len-skip on k-blocks never read by the K-trimmed mlp2c.
__global__ __launch_bounds__(256) void ggemm(
    const short* __restrict__ embb, const int* __restrict__ s1c, const int* __restrict__ s2c,
    const short* __restrict__ W1bt, short* __restrict__ G1t, short* __restrict__ G2t,
    const int* __restrict__ len1, const int* __restrict__ len2, int nbc)
{
  __shared__ __align__(16) short U[208*64];      // transpose buffer (epilogue only)
  __shared__ __align__(16) short Bs[224*PAD];
  __shared__ int IdxS[64];
  const int tid=threadIdx.x, lane=tid&63, w=tid>>6, quad=lane>>4, ln=lane&15;
  const int rt=w&1, ch=w>>1;
  const int spp = 4*nbc;
  const int side = (blockIdx.x >= spp) ? 1 : 0;
  int lin = blockIdx.x - side*spp;
  int b, rb;
  if (nbc >= 8){ int sup=lin>>5, rem=lin&31; rb=rem>>3; b=sup*8+(rem&7); }
  else { b = lin>>2; rb = lin&3; }
  const int krow0 = rb*64;
  const int lenv = (side ? len2 : len1)[b];
  if (krow0 >= lenv) return;                     // skipped Gt columns are exactly those never read
  const int* idx = side ? s2c : s1c;
  short* Gt = (side ? G2t : G1t) + (size_t)b*GSTR;
  if (tid < 64) IdxS[tid] = idx[b*SL + krow0 + tid];
  __syncthreads();
  f32x4 acc0[7], acc1[7];
  #pragma unroll
  for (int t=0;t<7;t++){ acc0[t]=(f32x4){0,0,0,0}; acc1[t]=(f32x4){0,0,0,0}; }
  const int r_ = tid>>2, c_ = tid&3;
  const short* aP0 = &embb[(size_t)IdxS[rt*32+ln]*EP];
  const short* aP1 = &embb[(size_t)IdxS[rt*32+16+ln]*EP];

  short8 bR0, bR1, bR2, bR3, aC0, aC1, aN0, aN1;
  bR0 = *(const short8*)&W1bt[(size_t)r_*EP + c_*8];
  bR1 = *(const short8*)&W1bt[(size_t)(64+r_)*EP + c_*8];
  bR2 = *(const short8*)&W1bt[(size_t)(128+r_)*EP + c_*8];
  if (r_<32) bR3 = ldg_row(W1bt, 192+r_, EP, c_*8);
  aC0 = *(const short8*)&aP0[quad*8];
  aC1 = *(const short8*)&aP1[quad*8];
  aN0 = *(const short8*)&aP0[32 + quad*8];
  aN1 = *(const short8*)&aP1[32 + quad*8];

  for (int ks=0; ks<10; ks++){
    __syncthreads();
    *(short8*)&Bs[r_*PAD + c_*8] = bR0;
    *(short8*)&Bs[(64+r_)*PAD + c_*8] = bR1;
    *(short8*)&Bs[(128+r_)*PAD + c_*8] = bR2;
    if (r_<32) *(short8*)&Bs[(192+r_)*PAD + c_*8] = bR3;
    __syncthreads();
    if (ks < 9){
      const int k0 = (ks+1)*32;
      bR0 = *(const short8*)&W1bt[(size_t)r_*EP + k0 + c_*8];
      bR1 = *(const short8*)&W1bt[(size_t)(64+r_)*EP + k0 + c_*8];
      bR2 = *(const short8*)&W1bt[(size_t)(128+r_)*EP + k0 + c_*8];
      if (r_<32) bR3 = ldg_row(W1bt, 192+r_, EP, k0 + c_*8);
    }
    short8 a0 = aC0, a1 = aC1;
    aC0 = aN0; aC1 = aN1;
    if (ks+2 < 10){
      aN0 = *(const short8*)&aP0[(ks+2)*32 + quad*8];
      aN1 = *(const short8*)&aP1[(ks+2)*32 + quad*8];
    }
    #pragma unroll
    for (int tt=0; tt<7; tt++){
      short8 bb = *(const short8*)&Bs[(ch*112 + tt*16 + ln)*PAD + quad*8];
      acc0[tt] = MFMA(a0, bb, acc0[tt]);
      acc1[tt] = MFMA(a1, bb, acc1[tt]);
    }
  }
  __syncthreads();
  // epilogue: XOR-swizzled LDS transpose (octet o of row n stored at o^(n&7)), no bias/relu
  #pragma unroll
  for (int tt=0; tt<7; tt++){
    int n = (ch*7+tt)*16+ln;
    if (n < 208){
      #pragma unroll
      for (int r=0;r<4;r++){
        int kl0 = rt*32 + quad*4 + r;
        int kl1 = kl0 + 16;
        U[n*64 + ((kl0>>3) ^ (n&7))*8 + (kl0&7)] = f2b(acc0[tt][r]);
        U[n*64 + ((kl1>>3) ^ (n&7))*8 + (kl1&7)] = f2b(acc1[tt][r]);
      }
    }
  }
  __syncthreads();
  #pragma unroll
  for (int it=0; it<7; it++){
    int p = it*256+tid, n = p>>3, oct = p&7;
    if (n < 208){
      short8 v = *(const short8*)&U[n*64 + (oct^(n&7))*8];
      *(short8*)&Gt[(size_t)n*SL + krow0 + oct*8] = v;
    }
  }
}

// ---------- compare MLP: M=64, 2x2 wave grid, direct-global A; layer1 = emb@W1cTop + P@Gt (len-trimmed) ----------
__global__ __launch_bounds__(256) void mlp2c(
    const short* __restrict__ embb,
    const int* __restrict__ s1c, const int* __restrict__ s2c,
    const short* __restrict__ Pb, const short* __restrict__ Pa,
    const short* __restrict__ G2t, const short* __restrict__ G1t,
    const short* __restrict__ W1tT, const float* __restrict__ b1,
    const short* __restrict__ W2t, const float* __restrict__ b2,
    const int* __restrict__ len1, const int* __restrict__ len2,
    float* __restrict__ v1, float* __restrict__ v2, int nbc)
{
  __shared__ __align__(16) short U[64*TSP];      // layer-1 output only
  __shared__ __align__(16) short Bs[224*PAD];
  __shared__ int IdxS[64];
  const int tid=threadIdx.x, lane=tid&63, w=tid>>6, quad=lane>>4, ln=lane&15;
  const int rt=w&1, ch=w>>1;
  const int spp = 4*nbc;
  const int side = (blockIdx.x >= spp) ? 1 : 0;
  int lin = blockIdx.x - side*spp;
  int b, rb;
  if (nbc >= 8){ int sup=lin>>5, rem=lin&31; rb=rem>>3; b=sup*8+(rem&7); }
  else { b = lin>>2; rb = lin&3; }
  const int prow0 = rb*64;
  const int* idx = side ? s2c : s1c;
  const short* P = (side ? Pa : Pb) + (size_t)b*SL*SL;
  const short* Gt = (side ? G1t : G2t) + (size_t)b*GSTR;
  const int lenK = side ? len1[b] : len2[b];     // K-extent of the P@Gt phase
  const int lenM = side ? len2[b] : len1[b];     // row mask for the final sum
  const int NK = 10 + ((lenK+31)>>5);
  float* V = side ? v2 : v1;
  if (tid < 64) IdxS[tid] = idx[b*SL + prow0 + tid];
  __syncthreads();

  f32x4 acc0[7], acc1[7];
  #pragma unroll
  for (int t=0;t<7;t++){ acc0[t]=(f32x4){0,0,0,0}; acc1[t]=(f32x4){0,0,0,0}; }
  const int r_ = tid>>2, c_ = tid&3;
  const short* aE0 = &embb[(size_t)IdxS[rt*32+ln]*EP];
  const short* aE1 = &embb[(size_t)IdxS[rt*32+16+ln]*EP];
  const short* aQ0 = P + (size_t)(prow0 + rt*32 + ln)*SL;
  const short* aQ1 = P + (size_t)(prow0 + rt*32 + 16 + ln)*SL;

  auto loadA = [&](int ks, const short* aE, const short* aQ)->short8 {
    if (ks < 10) return *(const short8*)&aE[ks*32 + quad*8];
    return *(const short8*)&aQ[(ks-10)*32 + quad*8];
  };
  auto loadB = [&](int ks, int n)->short8 {
    if (n >= 208){ short8 z={0,0,0,0,0,0,0,0}; return z; }
    if (ks < 10) return *(const short8*)&W1tT[(size_t)n*EP + ks*32 + c_*8];
    return *(const short8*)&Gt[(size_t)n*SL + (ks-10)*32 + c_*8];
  };

  short8 bR0, bR1, bR2, bR3, aC0, aC1, aN0, aN1;
  bR0 = loadB(0, r_); bR1 = loadB(0, 64+r_); bR2 = loadB(0, 128+r_);
  if (r_<32) bR3 = loadB(0, 192+r_);
  aC0 = loadA(0, aE0, aQ0);
  aC1 = loadA(0, aE1, aQ1);
  aN0 = loadA(1, aE0, aQ0);
  aN1 = loadA(1, aE1, aQ1);

  // ---- layer 1: NK fused K-steps (10 emb@W1cTop + ceil(lenK/32) P@Gt) ----
  for (int ks=0; ks<NK; ks++){
    __syncthreads();
    *(short8*)&Bs[r_*PAD + c_*8] = bR0;
    *(short8*)&Bs[(64+r_)*PAD + c_*8] = bR1;
    *(short8*)&Bs[(128+r_)*PAD + c_*8] = bR2;
    if (r_<32) *(short8*)&Bs[(192+r_)*PAD + c_*8] = bR3;
    __syncthreads();
    if (ks+1 < NK){
      bR0 = loadB(ks+1, r_); bR1 = loadB(ks+1, 64+r_); bR2 = loadB(ks+1, 128+r_);
      if (r_<32) bR3 = loadB(ks+1, 192+r_);
    }
    short8 a0 = aC0, a1 = aC1;
    aC0 = aN0; aC1 = aN1;
    if (ks+2 < NK){
      aN0 = loadA(ks+2, aE0, aQ0);
      aN1 = loadA(ks+2, aE1, aQ1);
    }
    #pragma unroll
    for (int tt=0; tt<7; tt++){
      short8 bb = *(const short8*)&Bs[(ch*112 + tt*16 + ln)*PAD + quad*8];
      acc0[tt] = MFMA(a0, bb, acc0[tt]);
      acc1[tt] = MFMA(a1, bb, acc1[tt]);
    }
  }
  // bias + relu -> U (cols >= HD written zero)
  #pragma unroll
  for (int tt=0; tt<7; tt++){
    int col = (ch*7+tt)*16+ln;
    float bv = (col<HD) ? b1[col] : 0.f;
    #pragma unroll
    for (int r=0;r<4;r++){
      int rl = rt*32 + quad*4 + r;
      U[(rl   )*TSP + col] = f2b((col<HD) ? fmaxf(acc0[tt][r]+bv, 0.f) : 0.f);
      U[(rl+16)*TSP + col] = f2b((col<HD) ? fmaxf(acc1[tt][r]+bv, 0.f) : 0.f);
    }
    acc0[tt]=(f32x4){0,0,0,0}; acc1[tt]=(f32x4){0,0,0,0};
  }

  // ---- layer 2 (K=224, 7 steps) ----
  bR0 = *(const short8*)&W2t[(size_t)r_*HP + c_*8];
  bR1 = *(const short8*)&W2t[(size_t)(64+r_)*HP + c_*8];
  bR2 = *(const short8*)&W2t[(size_t)(128+r_)*HP + c_*8];
  if (r_<32) bR3 = ldg_row(W2t, 192+r_, HP, c_*8);
  for (int ks=0; ks<7; ks++){
    __syncthreads();   // first iter: covers epilogue U writes + last layer-1 Bs reads
    *(short8*)&Bs[r_*PAD + c_*8] = bR0;
    *(short8*)&Bs[(64+r_)*PAD + c_*8] = bR1;
    *(short8*)&Bs[(128+r_)*PAD + c_*8] = bR2;
    if (r_<32) *(short8*)&Bs[(192+r_)*PAD + c_*8] = bR3;
    __syncthreads();
    if (ks < 6){
      const int k0 = (ks+1)*32;
      bR0 = *(const short8*)&W2t[(size_t)r_*HP + k0 + c_*8];
      bR1 = *(const short8*)&W2t[(size_t)(64+r_)*HP + k0 + c_*8];
      bR2 = *(const short8*)&W2t[(size_t)(128+r_)*HP + k0 + c_*8];
      if (r_<32) bR3 = ldg_row(W2t, 192+r_, HP, k0 + c_*8);
    }
    short8 a0 = *(const short8*)&U[(rt*32+ln)*TSP + ks*32 + quad*8];
    short8 a1 = *(const short8*)&U[(rt*32+16+ln)*TSP + ks*32 + quad*8];
    #pragma unroll
    for (int tt=0; tt<7; tt++){
      short8 bb = *(const short8*)&Bs[(ch*112 + tt*16 + ln)*PAD + quad*8];
      acc0[tt] = MFMA(a0, bb, acc0[tt]);
      acc1[tt] = MFMA(a1, bb, acc1[tt]);
    }
  }
  // masked row-sum epilogue (32 rows per wave-half via acc0/acc1, quad-reduced)
  {
    const int posBase = prow0 + rt*32 + quad*4;
    #pragma unroll
    for (int tt=0; tt<7; tt++){
      int col = (ch*7+tt)*16+ln;
      float bv = (col<HD) ? b2[col] : 0.f;
      float s = 0.f;
      #pragma unroll
      for (int r=0;r<4;r++){
        float v0 = fmaxf(acc0[tt][r]+bv, 0.f); if (posBase    + r < lenM) s += v0;
        float v1_ = fmaxf(acc1[tt][r]+bv, 0.f); if (posBase+16 + r < lenM) s += v1_;
      }
      s += __shfl_xor(s,16);
      s += __shfl_xor(s,32);
      if (quad==0 && col<HD) atomicAdd(&V[b*HD+col], s);
    }
  }
}

// ---------- aggregate ----------
__global__ __launch_bounds__(256) void aggregate(
    const float* __restrict__ v1, const float* __restrict__ v2,
    const float* __restrict__ W1g, const float* __restrict__ b1g,
    const float* __restrict__ W2g, const float* __restrict__ b2g,
    float* __restrict__ out)
{
  __shared__ float z[2*HD];
  __shared__ float a[HD];
  const int b = blockIdx.x, t = threadIdx.x;
  if (t < HD){ z[t] = v1[b*HD+t]; z[HD+t] = v2[b*HD+t]; }
  __syncthreads();
  if (t < HD){
    float acc = b1g[t];
    for (int k=0;k<2*HD;k++) acc += z[k]*W1g[(size_t)k*HD+t];
    a[t] = fmaxf(acc, 0.f);
  }
  __syncthreads();
  if (t < 2){
    float acc = b2g[t];
    for (int k=0;k<HD;k++) acc += a[k]*W2g[k*2+t];
    out[b*2+t] = acc;
  }
}

extern "C" void kernel_launch(void* const* d_in, const int* in_sizes, int n_in,
                              void* d_out, int out_size, void* d_ws, size_t ws_size,
                              hipStream_t stream) {
  const float* emb = (const float*)d_in[0];
  const float* W1a = (const float*)d_in[1];  const float* b1a = (const float*)d_in[2];
  const float* W2a = (const float*)d_in[3];  const float* b2a = (const float*)d_in[4];
  const float* W1c = (const float*)d_in[5];  const float* b1c = (const float*)d_in[6];
  const float* W2c = (const float*)d_in[7];  const float* b2c = (const float*)d_in[8];
  const float* W1g = (const float*)d_in[9];  const float* b1g = (const float*)d_in[10];
  const float* W2g = (const float*)d_in[11]; const float* b2g = (const float*)d_in[12];
  const int* s1 = (const int*)d_in[13];
  const int* s2 = (const int*)d_in[14];
  const int* len1 = (const int*)d_in[15];
  const int* len2 = (const int*)d_in[16];
  float* out = (float*)d_out;
  char* W = (char*)d_ws;

  // ---- fixed region ----
  float* v1    = (float*)(W);                      // 409,600
  float* v2    = (float*)(W + 409600);             // 409,600
  short* embb  = (short*)(W + 819200);             // 32,000,000
  short* W1at  = (short*)(W + 32819200);           // 133,120
  short* W2at  = (short*)(W + 32952320);           //  93,184
  short* W1ctT = (short*)(W + 33045504);           // 133,120
  short* W1cbT = (short*)(W + 33178624);           // 133,120
  short* W2ct  = (short*)(W + 33311744);           //  93,184
  char*  C0    = W + 33404928;
  const size_t FIXED = 33404928ull;

  // ---- per-batch chunked region ----
  const size_t PERB = 968704ull;
  int nbc = NB;
  while (nbc > 1 && FIXED + (size_t)nbc*PERB > ws_size) nbc >>= 1;
  const size_t nb = (size_t)nbc;
  short*    h1  = (short*)(C0);
  short*    h2  = (short*)(C0 + nb*114688);
  float*    e   = (float*)(C0 + nb*229376);
  short*    Pa  = (short*)(C0 + nb*491520);
  short*    Pb  = (short*)(C0 + nb*622592);
  short*    G1t = (short*)(C0 + nb*753664);
  short*    G2t = (short*)(C0 + nb*860160);
  unsigned* Rm  = (unsigned*)(C0 + nb*966656);
  unsigned* Cm  = (unsigned*)(C0 + nb*967680);

  const dim3 blk(256);
  hipMemsetAsync(v1, 0, 2ull*NB*HD*sizeof(float), stream);
  conv_emb<<<dim3((50000*EP+255)/256), blk, 0, stream>>>(emb, embb);
  convT_plain<<<dim3((208*EP+255)/256), blk, 0, stream>>>(W1a, W1at, ED, EP);
  convT_plain<<<dim3((208*HP+255)/256), blk, 0, stream>>>(W2a, W2at, HD, HP);
  convT_plain<<<dim3((208*EP+255)/256), blk, 0, stream>>>(W1c, W1ctT, ED, EP);
  convT_plain<<<dim3((208*EP+255)/256), blk, 0, stream>>>(W1c + (size_t)ED*HD, W1cbT, ED, EP);
  convT_plain<<<dim3((208*HP+255)/256), blk, 0, stream>>>(W2c, W2ct, HD, HP);

  const int chunks = NB / nbc;
  for (int c = 0; c < chunks; c++){
    const int b0 = c * nbc;
    const int* s1c = s1 + (size_t)b0*SL;
    const int* s2c = s2 + (size_t)b0*SL;
    const int* l1c = len1 + b0;
    const int* l2c = len2 + b0;

    hipMemsetAsync(Rm, 0, (size_t)nbc*SL*8, stream);   // Rm + Cm (contiguous), e>=0 so 0 is -inf
    mlp2<<<dim3(8*nbc), blk, 0, stream>>>(embb, s1c, s2c, W1at, b1a, W2at, b2a, h1, h2);
    scores_gemm<<<dim3(4,4,nbc), blk, 0, stream>>>(h1, h2, e, Rm, Cm);
    pwrite_k<<<dim3(4,2,nbc), blk, 0, stream>>>(e, Rm, Cm, l1c, l2c, Pa, Pb);
    ggemm<<<dim3(8*nbc), blk, 0, stream>>>(embb, s1c, s2c, W1cbT, G1t, G2t, l1c, l2c, nbc);
    mlp2c<<<dim3(8*nbc), blk, 0, stream>>>(embb, s1c, s2c, Pb, Pa, G2t, G1t,
                                           W1ctT, b1c, W2ct, b2c, l1c, l2c,
                                           v1 + (size_t)b0*HD, v2 + (size_t)b0*HD, nbc);
  }
  aggregate<<<dim3(NB), blk, 0, stream>>>(v1, v2, W1g, b1g, W2g, b2g, out);
}

// Round 7
// 749.986 us; speedup vs baseline: 1.2561x; 1.2561x over previous
//
#include <hip/hip_runtime.h>
#include <hip/hip_bf16.h>

#define DEV static __device__ __forceinline__

typedef short short8 __attribute__((ext_vector_type(8)));
typedef short short4v __attribute__((ext_vector_type(4)));
typedef float f32x4 __attribute__((ext_vector_type(4)));

#define NB 512
#define SL 256
#define ED 300
#define HD 200
#define EP 320   // padded embed stride
#define HP 224   // padded hidden stride
#define TSP 232  // LDS layer-1 output tile stride
#define PAD 40
#define GSTR 53248   // per-(b,side) Gt size in shorts: 208*256

#define MFMA(a,b,c) __builtin_amdgcn_mfma_f32_16x16x32_bf16(a,b,c,0,0,0)

DEV short f2b(float f){ __hip_bfloat16 h = __float2bfloat16(f); short s; __builtin_memcpy(&s,&h,2); return s; }

// zero-guarded weight-row loader (rows >= 208 read as zero)
DEV short8 ldg_row(const short* __restrict__ Wt, int n, size_t stride, int off){
  if (n < 208) return *(const short8*)&Wt[(size_t)n*stride + off];
  short8 z = {0,0,0,0,0,0,0,0};
  return z;
}

// ---------- one-time conversions ----------
__global__ __launch_bounds__(256) void conv_emb(const float* __restrict__ src, short* __restrict__ dst){
  size_t g = (size_t)blockIdx.x*256 + threadIdx.x;
  if (g >= (size_t)50000*EP) return;
  int row = (int)(g/EP), k = (int)(g%EP);
  dst[g] = (k<ED) ? f2b(src[(size_t)row*ED + k]) : (short)0;
}
// Wt[n][k] (208 x KP) <- W[k][n] (Kreal x 200), zero padded
__global__ __launch_bounds__(256) void convT_plain(const float* __restrict__ W, short* __restrict__ Wt,
                                                   int Kreal, int KP){
  int g = blockIdx.x*256 + threadIdx.x;
  if (g >= 208*KP) return;
  int n = g/KP, k = g%KP;
  float v = (n<HD && k<Kreal) ? W[(size_t)k*HD + n] : 0.f;
  Wt[g] = f2b(v);
}

// ---------- fused 2-layer attend MLP, 512 threads / 8 waves ----------
// M=64 rows/block; waves in 4x2 grid: wr = row-group of 16, wc = col-half (7 of 14 tiles).
// Data movement identical to the proven 4-wave version; 2x the waves for latency hiding.
__global__ __launch_bounds__(512) void mlp2(
    const short* __restrict__ embb,
    const int* __restrict__ idxA, const int* __restrict__ idxB,
    const short* __restrict__ W1t, const float* __restrict__ b1,
    const short* __restrict__ W2t, const float* __restrict__ b2,
    short* __restrict__ OutA, short* __restrict__ OutB)
{
  __shared__ __align__(16) short U[64*TSP];      // A-stage (first 64*PAD) / layer-1 out union
  __shared__ __align__(16) short Bs[224*PAD];
  __shared__ int IdxS[64];
  const int tid=threadIdx.x, lane=tid&63, w=tid>>6, quad=lane>>4, ln=lane&15;
  const int wr=w>>1, wc=w&1;
  const int half = gridDim.x>>1;
  const int side = (blockIdx.x >= half) ? 1 : 0;
  const int row0 = (blockIdx.x - side*half)*64;
  const int* idx = side ? idxB : idxA;
  if (tid < 64) IdxS[tid] = idx[row0+tid];
  __syncthreads();

  f32x4 acc[7];
  #pragma unroll
  for (int t=0;t<7;t++) acc[t]=(f32x4){0,0,0,0};
  const int r_ = tid>>2, c_ = tid&3;      // r_: 0..127
  const int ar = r_;                      // A row for tid<256 (0..63)
  const size_t arow = (tid<256) ? (size_t)IdxS[ar]*EP : 0;

  short8 aR, bR0, bR1;
  if (tid<256) aR = *(const short8*)&embb[arow + c_*8];
  bR0 = *(const short8*)&W1t[(size_t)r_*EP + c_*8];
  if (r_<96) bR1 = ldg_row(W1t, 128+r_, EP, c_*8);

  // ---- layer 1 (K=320, 10 steps) ----
  for (int ks=0; ks<10; ks++){
    __syncthreads();
    if (tid<256) *(short8*)&U[ar*PAD + c_*8] = aR;
    *(short8*)&Bs[r_*PAD + c_*8] = bR0;
    if (r_<96) *(short8*)&Bs[(128+r_)*PAD + c_*8] = bR1;
    __syncthreads();
    if (ks < 9){
      const int k0 = (ks+1)*32;
      if (tid<256) aR = *(const short8*)&embb[arow + k0 + c_*8];
      bR0 = *(const short8*)&W1t[(size_t)r_*EP + k0 + c_*8];
      if (r_<96) bR1 = ldg_row(W1t, 128+r_, EP, k0 + c_*8);
    }
    short8 a = *(const short8*)&U[(wr*16+ln)*PAD + quad*8];
    #pragma unroll
    for (int tt=0; tt<7; tt++){
      short8 bb = *(const short8*)&Bs[(wc*112 + tt*16 + ln)*PAD + quad*8];
      acc[tt] = MFMA(a, bb, acc[tt]);
    }
  }
  __syncthreads();                       // all A-stage reads done before Ts overwrites U
  // layer-1 epilogue -> U (stride TSP); cols >= HD written zero (covers 200..223)
  #pragma unroll
  for (int tt=0; tt<7; tt++){
    int col = (wc*7+tt)*16+ln;
    float bv = (col<HD) ? b1[col] : 0.f;
    #pragma unroll
    for (int r=0;r<4;r++){
      int rl = wr*16 + quad*4 + r;
      U[rl*TSP + col] = f2b((col<HD) ? fmaxf(acc[tt][r]+bv, 0.f) : 0.f);
    }
    acc[tt]=(f32x4){0,0,0,0};
  }

  // ---- layer 2 (K=224, 7 steps) ----
  bR0 = *(const short8*)&W2t[(size_t)r_*HP + c_*8];
  if (r_<96) bR1 = ldg_row(W2t, 128+r_, HP, c_*8);
  for (int ks=0; ks<7; ks++){
    __syncthreads();   // first iter: covers epilogue U writes + last layer-1 Bs reads
    *(short8*)&Bs[r_*PAD + c_*8] = bR0;
    if (r_<96) *(short8*)&Bs[(128+r_)*PAD + c_*8] = bR1;
    __syncthreads();
    if (ks < 6){
      const int k0 = (ks+1)*32;
      bR0 = *(const short8*)&W2t[(size_t)r_*HP + k0 + c_*8];
      if (r_<96) bR1 = ldg_row(W2t, 128+r_, HP, k0 + c_*8);
    }
    short8 a = *(const short8*)&U[(wr*16+ln)*TSP + ks*32 + quad*8];
    #pragma unroll
    for (int tt=0; tt<7; tt++){
      short8 bb = *(const short8*)&Bs[(wc*112 + tt*16 + ln)*PAD + quad*8];
      acc[tt] = MFMA(a, bb, acc[tt]);
    }
  }
  short* Out = side ? OutB : OutA;
  #pragma unroll
  for (int tt=0; tt<7; tt++){
    int col = (wc*7+tt)*16+ln;
    float bv = (col<HD) ? b2[col] : 0.f;
    #pragma unroll
    for (int r=0;r<4;r++){
      int rl = wr*16 + quad*4 + r;
      Out[(size_t)(row0+rl)*HP + col] = f2b((col<HD) ? fmaxf(acc[tt][r]+bv, 0.f) : 0.f);
    }
  }
}

// ---------- scores + fused row/col max (e >= 0 since h >= 0) ----------
__global__ __launch_bounds__(256) void scores_gemm(
    const short* __restrict__ h1, const short* __restrict__ h2, float* __restrict__ e,
    unsigned* __restrict__ RmU, unsigned* __restrict__ CmU)
{
  __shared__ __align__(16) short As[64*PAD];
  __shared__ __align__(16) short Bs[64*PAD];
  const int b = blockIdx.z;
  const int i0 = blockIdx.x*64, j0 = blockIdx.y*64;
  const int tid=threadIdx.x, lane=tid&63, w=tid>>6, quad=lane>>4, ln=lane&15;
  const int r_ = tid>>2, c_ = tid&3;
  f32x4 acc[4];
  #pragma unroll
  for (int t=0;t<4;t++) acc[t]=(f32x4){0.f,0.f,0.f,0.f};
  const short* Arow = &h1[((size_t)b*SL + i0 + r_)*HP + c_*8];
  const short* Brow = &h2[((size_t)b*SL + j0 + r_)*HP + c_*8];
  short8 aR = *(const short8*)Arow;
  short8 bR = *(const short8*)Brow;
  for (int ks=0; ks<7; ks++){
    __syncthreads();
    *(short8*)&As[r_*PAD + c_*8] = aR;
    *(short8*)&Bs[r_*PAD + c_*8] = bR;
    __syncthreads();
    if (ks < 6){
      aR = *(const short8*)(Arow + (ks+1)*32);
      bR = *(const short8*)(Brow + (ks+1)*32);
    }
    short8 a = *(const short8*)&As[(w*16+ln)*PAD + quad*8];
    #pragma unroll
    for (int t=0;t<4;t++){
      short8 bb = *(const short8*)&Bs[(t*16+ln)*PAD + quad*8];
      acc[t] = MFMA(a, bb, acc[t]);
    }
  }
  #pragma unroll
  for (int t=0;t<4;t++){
    int j = j0 + t*16 + ln;
    #pragma unroll
    for (int r=0;r<4;r++){
      int i = i0 + w*16 + quad*4 + r;
      e[(size_t)b*SL*SL + (size_t)i*SL + j] = acc[t][r];
    }
  }
  // row maxes (over j): reduce over ln within quad-group
  #pragma unroll
  for (int r=0;r<4;r++){
    float m = fmaxf(fmaxf(acc[0][r],acc[1][r]), fmaxf(acc[2][r],acc[3][r]));
    m=fmaxf(m,__shfl_xor(m,1)); m=fmaxf(m,__shfl_xor(m,2));
    m=fmaxf(m,__shfl_xor(m,4)); m=fmaxf(m,__shfl_xor(m,8));
    if (ln==0) atomicMax(&RmU[b*SL + i0 + w*16 + quad*4 + r], __float_as_uint(m));
  }
  // col maxes (over i): reduce over quad
  #pragma unroll
  for (int t=0;t<4;t++){
    float m = fmaxf(fmaxf(acc[t][0],acc[t][1]), fmaxf(acc[t][2],acc[t][3]));
    m=fmaxf(m,__shfl_xor(m,16)); m=fmaxf(m,__shfl_xor(m,32));
    if (quad==0) atomicMax(&CmU[b*SL + j0 + t*16 + ln], __float_as_uint(m));
  }
}

// ---------- P weights, normalized + masked + row-zeroed ----------
__global__ __launch_bounds__(256) void pwrite_k(
    const float* __restrict__ e, const unsigned* __restrict__ RmU, const unsigned* __restrict__ CmU,
    const int* __restrict__ len1, const int* __restrict__ len2,
    short* __restrict__ Pa, short* __restrict__ Pb)
{
  const int b = blockIdx.z, s = blockIdx.x, ori = blockIdx.y;
  const float* eb = e + (size_t)b*SL*SL;
  const int tid = threadIdx.x, lane = tid&63, w = tid>>6;
  if (ori == 0){
    const int l1 = len1[b], l2 = len2[b];
    if (s*64 >= l1) return;          // rows >= l1 are stale; masked out downstream
    for (int t=0;t<16;t++){
      int i = s*64 + w*16 + t;
      if (i >= l1) break;
      float cm = __uint_as_float(CmU[b*SL+i]);
      float4 v = ((const float4*)(eb + (size_t)i*SL))[lane];
      int c0 = lane*4;
      float e0 = (c0+0<l2) ? __expf(fminf(v.x-cm,85.f)) : 0.f;
      float e1 = (c0+1<l2) ? __expf(fminf(v.y-cm,85.f)) : 0.f;
      float e2 = (c0+2<l2) ? __expf(fminf(v.z-cm,85.f)) : 0.f;
      float e3 = (c0+3<l2) ? __expf(fminf(v.w-cm,85.f)) : 0.f;
      float ss = e0+e1+e2+e3;
      ss+=__shfl_xor(ss,1); ss+=__shfl_xor(ss,2); ss+=__shfl_xor(ss,4);
      ss+=__shfl_xor(ss,8); ss+=__shfl_xor(ss,16); ss+=__shfl_xor(ss,32);
      float inv = (ss>0.f) ? 1.f/ss : 0.f;
      short4v o; o[0]=f2b(e0*inv); o[1]=f2b(e1*inv); o[2]=f2b(e2*inv); o[3]=f2b(e3*inv);
      ((short4v*)(Pb + (size_t)b*SL*SL + (size_t)i*SL))[lane] = o;
    }
  } else {
    __shared__ float Part[4][64];
    __shared__ float SaInv[64];
    __shared__ float RmS[64];
    __shared__ float Tile[64][65];
    const int l1 = len1[b], l2 = len2[b];
    const int j0 = s*64;
    if (tid < 64) RmS[tid] = __uint_as_float(RmU[b*SL + j0 + tid]);
    __syncthreads();
    {
      float sum = 0.f;
      for (int i=w; i<l1; i+=4)
        sum += __expf(fminf(eb[(size_t)i*SL + j0 + lane] - RmS[lane], 85.f));
      Part[w][lane] = sum;
    }
    __syncthreads();
    if (w==0){
      float s_ = Part[0][lane]+Part[1][lane]+Part[2][lane]+Part[3][lane];
      SaInv[lane] = (s_>0.f && (j0+lane)<l2) ? 1.f/s_ : 0.f;  // j>=l2: zero row (mask2 on alphas)
    }
    __syncthreads();
    // only Pa columns < round_up_32(l1) are ever read by the K-trimmed mlp2c
    const int kmax = (l1+31)&~31;
    const int nti = (kmax+63)>>6;
    for (int ti=0; ti<nti; ti++){
      const int i0 = ti*64;
      #pragma unroll 4
      for (int it=0; it<16; it++){
        int il = it*4 + w;
        int i = i0 + il;
        float v = eb[(size_t)i*SL + j0 + lane];
        float p = (i<l1) ? __expf(fminf(v - RmS[lane],85.f))*SaInv[lane] : 0.f;
        Tile[il][lane] = p;
      }
      __syncthreads();
      {
        int jl = tid>>2, q = tid&3;
        short8 o1, o2;
        #pragma unroll
        for (int u=0;u<8;u++){
          o1[u] = f2b(Tile[q*16+u][jl]);
          o2[u] = f2b(Tile[q*16+8+u][jl]);
        }
        short* dst = Pa + (size_t)b*SL*SL + (size_t)(j0+jl)*SL + i0 + q*16;
        *(short8*)dst = o1;
        *(short8*)(dst+8) = o2;
      }
      __syncthreads();
    }
  }
}

// ---------- ggemm: Gt[n][k], 512 threads / 8 waves (4x2), len-skip ----------
__global__ __launch_bounds__(512) void ggemm(
    const short* __restrict__ embb, const int* __restrict__ s1c, const int* __restrict__ s2c,
    const short* __restrict__ W1bt, short* __restrict__ G1t, short* __restrict__ G2t,
    const int* __restrict__ len1, const int* __restrict__ len2, int nbc)
{
  __shared__ __align__(16) short U[208*64];      // A-stage (first 64*PAD) / transpose buffer
  __shared__ __align__(16) short Bs[224*PAD];
  __shared__ int IdxS[64];
  const int tid=threadIdx.x, lane=tid&63, w=tid>>6, quad=lane>>4, ln=lane&15;
  const int wr=w>>1, wc=w&1;
  const int spp = 4*nbc;
  const int side = (blockIdx.x >= spp) ? 1 : 0;
  int lin = blockIdx.x - side*spp;
  int b, rb;
  if (nbc >= 8){ int sup=lin>>5, rem=lin&31; rb=rem>>3; b=sup*8+(rem&7); }
  else { b = lin>>2; rb = lin&3; }
  const int krow0 = rb*64;
  const int lenv = (side ? len2 : len1)[b];
  if (krow0 >= lenv) return;                     // skipped Gt columns are exactly those never read
  const int* idx = side ? s2c : s1c;
  short* Gt = (side ? G2t : G1t) + (size_t)b*GSTR;
  if (tid < 64) IdxS[tid] = idx[b*SL + krow0 + tid];
  __syncthreads();
  f32x4 acc[7];
  #pragma unroll
  for (int t=0;t<7;t++) acc[t]=(f32x4){0,0,0,0};
  const int r_ = tid>>2, c_ = tid&3;
  const int ar = r_;
  const size_t arow = (tid<256) ? (size_t)IdxS[ar]*EP : 0;

  short8 aR, bR0, bR1;
  if (tid<256) aR = *(const short8*)&embb[arow + c_*8];
  bR0 = *(const short8*)&W1bt[(size_t)r_*EP + c_*8];
  if (r_<96) bR1 = ldg_row(W1bt, 128+r_, EP, c_*8);

  for (int ks=0; ks<10; ks++){
    __syncthreads();
    if (tid<256) *(short8*)&U[ar*PAD + c_*8] = aR;
    *(short8*)&Bs[r_*PAD + c_*8] = bR0;
    if (r_<96) *(short8*)&Bs[(128+r_)*PAD + c_*8] = bR1;
    __syncthreads();
    if (ks < 9){
      const int k0 = (ks+1)*32;
      if (tid<256) aR = *(const short8*)&embb[arow + k0 + c_*8];
      bR0 = *(const short8*)&W1bt[(size_t)r_*EP + k0 + c_*8];
      if (r_<96) bR1 = ldg_row(W1bt, 128+r_, EP, k0 + c_*8);
    }
    short8 a = *(const short8*)&U[(wr*16+ln)*PAD + quad*8];
    #pragma unroll
    for (int tt=0; tt<7; tt++){
      short8 bb = *(const short8*)&Bs[(wc*112 + tt*16 + ln)*PAD + quad*8];
      acc[tt] = MFMA(a, bb, acc[tt]);
    }
  }
  __syncthreads();
  // epilogue: XOR-swizzled LDS transpose (octet o of row n stored at o^(n&7)), no bias/relu
  #pragma unroll
  for (int tt=0; tt<7; tt++){
    int n = (wc*7+tt)*16+ln;
    if (n < 208){
      #pragma unroll
      for (int r=0;r<4;r++){
        int kl = wr*16 + quad*4 + r;
        U[n*64 + ((kl>>3) ^ (n&7))*8 + (kl&7)] = f2b(acc[tt][r]);
      }
    }
  }
  __syncthreads();
  #pragma unroll
  for (int it=0; it<4; it++){
    int p = it*512+tid, n = p>>3, oct = p&7;
    if (n < 208){
      short8 v = *(const short8*)&U[n*64 + (oct^(n&7))*8];
      *(short8*)&Gt[(size_t)n*SL + krow0 + oct*8] = v;
    }
  }
}

// ---------- compare MLP: 512 threads / 8 waves (4x2); layer1 = emb@W1cTop + P@Gt (len-trimmed) ----------
__global__ __launch_bounds__(512) void mlp2c(
    const short* __restrict__ embb,
    const int* __restrict__ s1c, const int* __restrict__ s2c,
    const short* __restrict__ Pb, const short* __restrict__ Pa,
    const short* __restrict__ G2t, const short* __restrict__ G1t,
    const short* __restrict__ W1tT, const float* __restrict__ b1,
    const short* __restrict__ W2t, const float* __restrict__ b2,
    const int* __restrict__ len1, const int* __restrict__ len2,
    float* __restrict__ v1, float* __restrict__ v2, int nbc)
{
  __shared__ __align__(16) short U[64*TSP];      // A-stage (first 64*PAD) / layer-1 out union
  __shared__ __align__(16) short Bs[224*PAD];
  __shared__ int IdxS[64];
  const int tid=threadIdx.x, lane=tid&63, w=tid>>6, quad=lane>>4, ln=lane&15;
  const int wr=w>>1, wc=w&1;
  const int spp = 4*nbc;
  const int side = (blockIdx.x >= spp) ? 1 : 0;
  int lin = blockIdx.x - side*spp;
  int b, rb;
  if (nbc >= 8){ int sup=lin>>5, rem=lin&31; rb=rem>>3; b=sup*8+(rem&7); }
  else { b = lin>>2; rb = lin&3; }
  const int prow0 = rb*64;
  const int* idx = side ? s2c : s1c;
  const short* P = (side ? Pa : Pb) + (size_t)b*SL*SL;
  const short* Gt = (side ? G1t : G2t) + (size_t)b*GSTR;
  const int lenK = side ? len1[b] : len2[b];     // K-extent of the P@Gt phase
  const int lenM = side ? len2[b] : len1[b];     // row mask for the final sum
  const int NK = 10 + ((lenK+31)>>5);
  float* V = side ? v2 : v1;
  if (tid < 64) IdxS[tid] = idx[b*SL + prow0 + tid];
  __syncthreads();

  f32x4 acc[7];
  #pragma unroll
  for (int t=0;t<7;t++) acc[t]=(f32x4){0,0,0,0};
  const int r_ = tid>>2, c_ = tid&3;
  const int ar = r_;
  const size_t arow = (tid<256) ? (size_t)IdxS[ar]*EP : 0;

  auto loadA = [&](int ks)->short8 {
    if (ks < 10) return *(const short8*)&embb[arow + ks*32 + c_*8];
    return *(const short8*)&P[(size_t)(prow0+ar)*SL + (ks-10)*32 + c_*8];
  };
  auto loadB = [&](int ks, int n)->short8 {
    if (n >= 208){ short8 z={0,0,0,0,0,0,0,0}; return z; }
    if (ks < 10) return *(const short8*)&W1tT[(size_t)n*EP + ks*32 + c_*8];
    return *(const short8*)&Gt[(size_t)n*SL + (ks-10)*32 + c_*8];
  };

  short8 aR, bR0, bR1;
  if (tid<256) aR = loadA(0);
  bR0 = loadB(0, r_);
  if (r_<96) bR1 = loadB(0, 128+r_);

  // ---- layer 1: NK fused K-steps (10 emb@W1cTop + ceil(lenK/32) P@Gt) ----
  for (int ks=0; ks<NK; ks++){
    __syncthreads();
    if (tid<256) *(short8*)&U[ar*PAD + c_*8] = aR;
    *(short8*)&Bs[r_*PAD + c_*8] = bR0;
    if (r_<96) *(short8*)&Bs[(128+r_)*PAD + c_*8] = bR1;
    __syncthreads();
    if (ks+1 < NK){
      if (tid<256) aR = loadA(ks+1);
      bR0 = loadB(ks+1, r_);
      if (r_<96) bR1 = loadB(ks+1, 128+r_);
    }
    short8 a = *(const short8*)&U[(wr*16+ln)*PAD + quad*8];
    #pragma unroll
    for (int tt=0; tt<7; tt++){
      short8 bb = *(const short8*)&Bs[(wc*112 + tt*16 + ln)*PAD + quad*8];
      acc[tt] = MFMA(a, bb, acc[tt]);
    }
  }
  __syncthreads();
  // bias + relu -> U (stride TSP); cols >= HD written zero
  #pragma unroll
  for (int tt=0; tt<7; tt++){
    int col = (wc*7+tt)*16+ln;
    float bv = (col<HD) ? b1[col] : 0.f;
    #pragma unroll
    for (int r=0;r<4;r++){
      int rl = wr*16 + quad*4 + r;
      U[rl*TSP + col] = f2b((col<HD) ? fmaxf(acc[tt][r]+bv, 0.f) : 0.f);
    }
    acc[tt]=(f32x4){0,0,0,0};
  }

  // ---- layer 2 (K=224, 7 steps) ----
  bR0 = *(const short8*)&W2t[(size_t)r_*HP + c_*8];
  if (r_<96) bR1 = ldg_row(W2t, 128+r_, HP, c_*8);
  for (int ks=0; ks<7; ks++){
    __syncthreads();   // first iter: covers epilogue U writes + last layer-1 Bs reads
    *(short8*)&Bs[r_*PAD + c_*8] = bR0;
    if (r_<96) *(short8*)&Bs[(128+r_)*PAD + c_*8] = bR1;
    __syncthreads();
    if (ks < 6){
      const int k0 = (ks+1)*32;
      bR0 = *(const short8*)&W2t[(size_t)r_*HP + k0 + c_*8];
      if (r_<96) bR1 = ldg_row(W2t, 128+r_, HP, k0 + c_*8);
    }
    short8 a = *(const short8*)&U[(wr*16+ln)*TSP + ks*32 + quad*8];
    #pragma unroll
    for (int tt=0; tt<7; tt++){
      short8 bb = *(const short8*)&Bs[(wc*112 + tt*16 + ln)*PAD + quad*8];
      acc[tt] = MFMA(a, bb, acc[tt]);
    }
  }
  // masked row-sum epilogue (16 rows per wave, quad-reduced)
  {
    const int posBase = prow0 + wr*16 + quad*4;
    #pragma unroll
    for (int tt=0; tt<7; tt++){
      int col = (wc*7+tt)*16+ln;
      float bv = (col<HD) ? b2[col] : 0.f;
      float s = 0.f;
      #pragma unroll
      for (int r=0;r<4;r++){
        float v = fmaxf(acc[tt][r]+bv, 0.f);
        if (posBase + r < lenM) s += v;
      }
      s += __shfl_xor(s,16);
      s += __shfl_xor(s,32);
      if (quad==0 && col<HD) atomicAdd(&V[b*HD+col], s);
    }
  }
}

// ---------- aggregate ----------
__global__ __launch_bounds__(256) void aggregate(
    const float* __restrict__ v1, const float* __restrict__ v2,
    const float* __restrict__ W1g, const float* __restrict__ b1g,
    const float* __restrict__ W2g, const float* __restrict__ b2g,
    float* __restrict__ out)
{
  __shared__ float z[2*HD];
  __shared__ float a[HD];
  const int b = blockIdx.x, t = threadIdx.x;
  if (t < HD){ z[t] = v1[b*HD+t]; z[HD+t] = v2[b*HD+t]; }
  __syncthreads();
  if (t < HD){
    float acc = b1g[t];
    for (int k=0;k<2*HD;k++) acc += z[k]*W1g[(size_t)k*HD+t];
    a[t] = fmaxf(acc, 0.f);
  }
  __syncthreads();
  if (t < 2){
    float acc = b2g[t];
    for (int k=0;k<HD;k++) acc += a[k]*W2g[k*2+t];
    out[b*2+t] = acc;
  }
}

extern "C" void kernel_launch(void* const* d_in, const int* in_sizes, int n_in,
                              void* d_out, int out_size, void* d_ws, size_t ws_size,
                              hipStream_t stream) {
  const float* emb = (const float*)d_in[0];
  const float* W1a = (const float*)d_in[1];  const float* b1a = (const float*)d_in[2];
  const float* W2a = (const float*)d_in[3];  const float* b2a = (const float*)d_in[4];
  const float* W1c = (const float*)d_in[5];  const float* b1c = (const float*)d_in[6];
  const float* W2c = (const float*)d_in[7];  const float* b2c = (const float*)d_in[8];
  const float* W1g = (const float*)d_in[9];  const float* b1g = (const float*)d_in[10];
  const float* W2g = (const float*)d_in[11]; const float* b2g = (const float*)d_in[12];
  const int* s1 = (const int*)d_in[13];
  const int* s2 = (const int*)d_in[14];
  const int* len1 = (const int*)d_in[15];
  const int* len2 = (const int*)d_in[16];
  float* out = (float*)d_out;
  char* W = (char*)d_ws;

  // ---- fixed region ----
  float* v1    = (float*)(W);                      // 409,600
  float* v2    = (float*)(W + 409600);             // 409,600
  short* embb  = (short*)(W + 819200);             // 32,000,000
  short* W1at  = (short*)(W + 32819200);           // 133,120
  short* W2at  = (short*)(W + 32952320);           //  93,184
  short* W1ctT = (short*)(W + 33045504);           // 133,120
  short* W1cbT = (short*)(W + 33178624);           // 133,120
  short* W2ct  = (short*)(W + 33311744);           //  93,184
  char*  C0    = W + 33404928;
  const size_t FIXED = 33404928ull;

  // ---- per-batch chunked region with lifetime overlays ----
  // R1 (262,144/batch): h1,h2 [mlp2 -> scores]  UNION  Pa,Pb [pwrite -> mlp2c]
  // R2 (262,144/batch): e     [scores -> pwrite] UNION  G1t,G2t [ggemm -> mlp2c]
  // RC (2,048/batch):   Rm, Cm
  const size_t PERB = 526336ull;
  int nbc = NB;
  while (nbc > 1 && FIXED + (size_t)nbc*PERB > ws_size) nbc >>= 1;
  const size_t nb = (size_t)nbc;
  char* R1 = C0;
  char* R2 = C0 + nb*262144;
  char* RC = C0 + nb*524288;
  short*    h1  = (short*)(R1);
  short*    h2  = (short*)(R1 + nb*114688);
  short*    Pa  = (short*)(R1);
  short*    Pb  = (short*)(R1 + nb*131072);
  float*    e   = (float*)(R2);
  short*    G1t = (short*)(R2);
  short*    G2t = (short*)(R2 + nb*106496);
  unsigned* Rm  = (unsigned*)(RC);
  unsigned* Cm  = (unsigned*)(RC + nb*1024);

  const dim3 blk(256);
  const dim3 blk512(512);
  hipMemsetAsync(v1, 0, 2ull*NB*HD*sizeof(float), stream);
  conv_emb<<<dim3((50000*EP+255)/256), blk, 0, stream>>>(emb, embb);
  convT_plain<<<dim3((208*EP+255)/256), blk, 0, stream>>>(W1a, W1at, ED, EP);
  convT_plain<<<dim3((208*HP+255)/256), blk, 0, stream>>>(W2a, W2at, HD, HP);
  convT_plain<<<dim3((208*EP+255)/256), blk, 0, stream>>>(W1c, W1ctT, ED, EP);
  convT_plain<<<dim3((208*EP+255)/256), blk, 0, stream>>>(W1c + (size_t)ED*HD, W1cbT, ED, EP);
  convT_plain<<<dim3((208*HP+255)/256), blk, 0, stream>>>(W2c, W2ct, HD, HP);

  const int chunks = NB / nbc;
  for (int c = 0; c < chunks; c++){
    const int b0 = c * nbc;
    const int* s1c = s1 + (size_t)b0*SL;
    const int* s2c = s2 + (size_t)b0*SL;
    const int* l1c = len1 + b0;
    const int* l2c = len2 + b0;

    hipMemsetAsync(Rm, 0, (size_t)nbc*SL*8, stream);   // Rm + Cm (contiguous), e>=0 so 0 is -inf
    mlp2<<<dim3(8*nbc), blk512, 0, stream>>>(embb, s1c, s2c, W1at, b1a, W2at, b2a, h1, h2);
    scores_gemm<<<dim3(4,4,nbc), blk, 0, stream>>>(h1, h2, e, Rm, Cm);
    pwrite_k<<<dim3(4,2,nbc), blk, 0, stream>>>(e, Rm, Cm, l1c, l2c, Pa, Pb);
    ggemm<<<dim3(8*nbc), blk512, 0, stream>>>(embb, s1c, s2c, W1cbT, G1t, G2t, l1c, l2c, nbc);
    mlp2c<<<dim3(8*nbc), blk512, 0, stream>>>(embb, s1c, s2c, Pb, Pa, G2t, G1t,
                                              W1ctT, b1c, W2ct, b2c, l1c, l2c,
                                              v1 + (size_t)b0*HD, v2 + (size_t)b0*HD, nbc);
  }
  aggregate<<<dim3(NB), blk, 0, stream>>>(v1, v2, W1g, b1g, W2g, b2g, out);
}

// Round 8
// 654.356 us; speedup vs baseline: 1.4397x; 1.1461x over previous
//
#include <hip/hip_runtime.h>
#include <hip/hip_bf16.h>

#define DEV static __device__ __forceinline__

typedef short short8 __attribute__((ext_vector_type(8)));
typedef short short4v __attribute__((ext_vector_type(4)));
typedef float f32x4 __attribute__((ext_vector_type(4)));

#define NB 512
#define SL 256
#define ED 300
#define HD 200
#define EP 320   // padded embed stride
#define HP 224   // padded hidden stride
#define TSP 232  // LDS layer-1 output tile stride
#define PAD 40
#define GSTR 53248   // per-(b,side) Gt size in shorts: 208*256

#define MFMA(a,b,c) __builtin_amdgcn_mfma_f32_16x16x32_bf16(a,b,c,0,0,0)

DEV short f2b(float f){ __hip_bfloat16 h = __float2bfloat16(f); short s; __builtin_memcpy(&s,&h,2); return s; }

// zero-guarded weight-row loader (rows >= 208 read as zero)
DEV short8 ldg_row(const short* __restrict__ Wt, int n, size_t stride, int off){
  if (n < 208) return *(const short8*)&Wt[(size_t)n*stride + off];
  short8 z = {0,0,0,0,0,0,0,0};
  return z;
}

// ---------- one-time conversions ----------
__global__ __launch_bounds__(256) void conv_emb(const float* __restrict__ src, short* __restrict__ dst){
  size_t g = (size_t)blockIdx.x*256 + threadIdx.x;
  if (g >= (size_t)50000*EP) return;
  int row = (int)(g/EP), k = (int)(g%EP);
  dst[g] = (k<ED) ? f2b(src[(size_t)row*ED + k]) : (short)0;
}
// Wt[n][k] (208 x KP) <- W[k][n] (Kreal x 200), zero padded
__global__ __launch_bounds__(256) void convT_plain(const float* __restrict__ W, short* __restrict__ Wt,
                                                   int Kreal, int KP){
  int g = blockIdx.x*256 + threadIdx.x;
  if (g >= 208*KP) return;
  int n = g/KP, k = g%KP;
  float v = (n<HD && k<Kreal) ? W[(size_t)k*HD + n] : 0.f;
  Wt[g] = f2b(v);
}

// ---------- fused 2-layer attend MLP, M=128, 512 threads / 8 waves (4 row x 2 col) ----------
// Wave = 32 rows (two 16-row fragments) x 7 of 14 N-tiles. B-dup amortized over 128 rows.
__global__ __launch_bounds__(512) void mlp2(
    const short* __restrict__ embb,
    const int* __restrict__ idxA, const int* __restrict__ idxB,
    const short* __restrict__ W1t, const float* __restrict__ b1,
    const short* __restrict__ W2t, const float* __restrict__ b2,
    short* __restrict__ OutA, short* __restrict__ OutB)
{
  __shared__ __align__(16) short U[128*TSP];     // A-stage (first 128*PAD) / layer-1 out union
  __shared__ __align__(16) short Bs[224*PAD];
  __shared__ int IdxS[128];
  const int tid=threadIdx.x, lane=tid&63, w=tid>>6, quad=lane>>4, ln=lane&15;
  const int wr=w>>1, wc=w&1;
  const int half = gridDim.x>>1;
  const int side = (blockIdx.x >= half) ? 1 : 0;
  const int row0 = (blockIdx.x - side*half)*128;
  const int* idx = side ? idxB : idxA;
  if (tid < 128) IdxS[tid] = idx[row0+tid];
  __syncthreads();

  f32x4 acc0[7], acc1[7];
  #pragma unroll
  for (int t=0;t<7;t++){ acc0[t]=(f32x4){0,0,0,0}; acc1[t]=(f32x4){0,0,0,0}; }
  const int r_ = tid>>2, c_ = tid&3;      // r_: 0..127
  const size_t arow = (size_t)IdxS[r_]*EP;

  short8 aR, bR0, bR1;
  aR  = *(const short8*)&embb[arow + c_*8];
  bR0 = *(const short8*)&W1t[(size_t)r_*EP + c_*8];
  if (r_<96) bR1 = ldg_row(W1t, 128+r_, EP, c_*8);

  // ---- layer 1 (K=320, 10 steps) ----
  for (int ks=0; ks<10; ks++){
    __syncthreads();
    *(short8*)&U[r_*PAD + c_*8] = aR;
    *(short8*)&Bs[r_*PAD + c_*8] = bR0;
    if (r_<96) *(short8*)&Bs[(128+r_)*PAD + c_*8] = bR1;
    __syncthreads();
    if (ks < 9){
      const int k0 = (ks+1)*32;
      aR  = *(const short8*)&embb[arow + k0 + c_*8];
      bR0 = *(const short8*)&W1t[(size_t)r_*EP + k0 + c_*8];
      if (r_<96) bR1 = ldg_row(W1t, 128+r_, EP, k0 + c_*8);
    }
    short8 a0 = *(const short8*)&U[(wr*32+ln)*PAD + quad*8];
    short8 a1 = *(const short8*)&U[(wr*32+16+ln)*PAD + quad*8];
    #pragma unroll
    for (int tt=0; tt<7; tt++){
      short8 bb = *(const short8*)&Bs[(wc*112 + tt*16 + ln)*PAD + quad*8];
      acc0[tt] = MFMA(a0, bb, acc0[tt]);
      acc1[tt] = MFMA(a1, bb, acc1[tt]);
    }
  }
  __syncthreads();                       // all A-stage reads done before layer-1 out overwrites U
  // layer-1 epilogue -> U (stride TSP); cols >= HD written zero (covers 200..223)
  #pragma unroll
  for (int tt=0; tt<7; tt++){
    int col = (wc*7+tt)*16+ln;
    float bv = (col<HD) ? b1[col] : 0.f;
    #pragma unroll
    for (int r=0;r<4;r++){
      int rl = wr*32 + quad*4 + r;
      U[(rl   )*TSP + col] = f2b((col<HD) ? fmaxf(acc0[tt][r]+bv, 0.f) : 0.f);
      U[(rl+16)*TSP + col] = f2b((col<HD) ? fmaxf(acc1[tt][r]+bv, 0.f) : 0.f);
    }
    acc0[tt]=(f32x4){0,0,0,0}; acc1[tt]=(f32x4){0,0,0,0};
  }

  // ---- layer 2 (K=224, 7 steps) ----
  bR0 = *(const short8*)&W2t[(size_t)r_*HP + c_*8];
  if (r_<96) bR1 = ldg_row(W2t, 128+r_, HP, c_*8);
  for (int ks=0; ks<7; ks++){
    __syncthreads();   // first iter: covers epilogue U writes + last layer-1 Bs reads
    *(short8*)&Bs[r_*PAD + c_*8] = bR0;
    if (r_<96) *(short8*)&Bs[(128+r_)*PAD + c_*8] = bR1;
    __syncthreads();
    if (ks < 6){
      const int k0 = (ks+1)*32;
      bR0 = *(const short8*)&W2t[(size_t)r_*HP + k0 + c_*8];
      if (r_<96) bR1 = ldg_row(W2t, 128+r_, HP, k0 + c_*8);
    }
    short8 a0 = *(const short8*)&U[(wr*32+ln)*TSP + ks*32 + quad*8];
    short8 a1 = *(const short8*)&U[(wr*32+16+ln)*TSP + ks*32 + quad*8];
    #pragma unroll
    for (int tt=0; tt<7; tt++){
      short8 bb = *(const short8*)&Bs[(wc*112 + tt*16 + ln)*PAD + quad*8];
      acc0[tt] = MFMA(a0, bb, acc0[tt]);
      acc1[tt] = MFMA(a1, bb, acc1[tt]);
    }
  }
  short* Out = side ? OutB : OutA;
  #pragma unroll
  for (int tt=0; tt<7; tt++){
    int col = (wc*7+tt)*16+ln;
    float bv = (col<HD) ? b2[col] : 0.f;
    #pragma unroll
    for (int r=0;r<4;r++){
      int rl = wr*32 + quad*4 + r;
      Out[(size_t)(row0+rl   )*HP + col] = f2b((col<HD) ? fmaxf(acc0[tt][r]+bv, 0.f) : 0.f);
      Out[(size_t)(row0+rl+16)*HP + col] = f2b((col<HD) ? fmaxf(acc1[tt][r]+bv, 0.f) : 0.f);
    }
  }
}

// ---------- scores + fused row/col max (e >= 0 since h >= 0) ----------
__global__ __launch_bounds__(256) void scores_gemm(
    const short* __restrict__ h1, const short* __restrict__ h2, float* __restrict__ e,
    unsigned* __restrict__ RmU, unsigned* __restrict__ CmU)
{
  __shared__ __align__(16) short As[64*PAD];
  __shared__ __align__(16) short Bs[64*PAD];
  const int b = blockIdx.z;
  const int i0 = blockIdx.x*64, j0 = blockIdx.y*64;
  const int tid=threadIdx.x, lane=tid&63, w=tid>>6, quad=lane>>4, ln=lane&15;
  const int r_ = tid>>2, c_ = tid&3;
  f32x4 acc[4];
  #pragma unroll
  for (int t=0;t<4;t++) acc[t]=(f32x4){0.f,0.f,0.f,0.f};
  const short* Arow = &h1[((size_t)b*SL + i0 + r_)*HP + c_*8];
  const short* Brow = &h2[((size_t)b*SL + j0 + r_)*HP + c_*8];
  short8 aR = *(const short8*)Arow;
  short8 bR = *(const short8*)Brow;
  for (int ks=0; ks<7; ks++){
    __syncthreads();
    *(short8*)&As[r_*PAD + c_*8] = aR;
    *(short8*)&Bs[r_*PAD + c_*8] = bR;
    __syncthreads();
    if (ks < 6){
      aR = *(const short8*)(Arow + (ks+1)*32);
      bR = *(const short8*)(Brow + (ks+1)*32);
    }
    short8 a = *(const short8*)&As[(w*16+ln)*PAD + quad*8];
    #pragma unroll
    for (int t=0;t<4;t++){
      short8 bb = *(const short8*)&Bs[(t*16+ln)*PAD + quad*8];
      acc[t] = MFMA(a, bb, acc[t]);
    }
  }
  #pragma unroll
  for (int t=0;t<4;t++){
    int j = j0 + t*16 + ln;
    #pragma unroll
    for (int r=0;r<4;r++){
      int i = i0 + w*16 + quad*4 + r;
      e[(size_t)b*SL*SL + (size_t)i*SL + j] = acc[t][r];
    }
  }
  // row maxes (over j): reduce over ln within quad-group
  #pragma unroll
  for (int r=0;r<4;r++){
    float m = fmaxf(fmaxf(acc[0][r],acc[1][r]), fmaxf(acc[2][r],acc[3][r]));
    m=fmaxf(m,__shfl_xor(m,1)); m=fmaxf(m,__shfl_xor(m,2));
    m=fmaxf(m,__shfl_xor(m,4)); m=fmaxf(m,__shfl_xor(m,8));
    if (ln==0) atomicMax(&RmU[b*SL + i0 + w*16 + quad*4 + r], __float_as_uint(m));
  }
  // col maxes (over i): reduce over quad
  #pragma unroll
  for (int t=0;t<4;t++){
    float m = fmaxf(fmaxf(acc[t][0],acc[t][1]), fmaxf(acc[t][2],acc[t][3]));
    m=fmaxf(m,__shfl_xor(m,16)); m=fmaxf(m,__shfl_xor(m,32));
    if (quad==0) atomicMax(&CmU[b*SL + j0 + t*16 + ln], __float_as_uint(m));
  }
}

// ---------- P weights, normalized + masked + row-zeroed ----------
__global__ __launch_bounds__(256) void pwrite_k(
    const float* __restrict__ e, const unsigned* __restrict__ RmU, const unsigned* __restrict__ CmU,
    const int* __restrict__ len1, const int* __restrict__ len2,
    short* __restrict__ Pa, short* __restrict__ Pb)
{
  const int b = blockIdx.z, s = blockIdx.x, ori = blockIdx.y;
  const float* eb = e + (size_t)b*SL*SL;
  const int tid = threadIdx.x, lane = tid&63, w = tid>>6;
  if (ori == 0){
    const int l1 = len1[b], l2 = len2[b];
    if (s*64 >= l1) return;          // rows >= l1 are stale; masked out downstream
    for (int t=0;t<16;t++){
      int i = s*64 + w*16 + t;
      if (i >= l1) break;
      float cm = __uint_as_float(CmU[b*SL+i]);
      float4 v = ((const float4*)(eb + (size_t)i*SL))[lane];
      int c0 = lane*4;
      float e0 = (c0+0<l2) ? __expf(fminf(v.x-cm,85.f)) : 0.f;
      float e1 = (c0+1<l2) ? __expf(fminf(v.y-cm,85.f)) : 0.f;
      float e2 = (c0+2<l2) ? __expf(fminf(v.z-cm,85.f)) : 0.f;
      float e3 = (c0+3<l2) ? __expf(fminf(v.w-cm,85.f)) : 0.f;
      float ss = e0+e1+e2+e3;
      ss+=__shfl_xor(ss,1); ss+=__shfl_xor(ss,2); ss+=__shfl_xor(ss,4);
      ss+=__shfl_xor(ss,8); ss+=__shfl_xor(ss,16); ss+=__shfl_xor(ss,32);
      float inv = (ss>0.f) ? 1.f/ss : 0.f;
      short4v o; o[0]=f2b(e0*inv); o[1]=f2b(e1*inv); o[2]=f2b(e2*inv); o[3]=f2b(e3*inv);
      ((short4v*)(Pb + (size_t)b*SL*SL + (size_t)i*SL))[lane] = o;
    }
  } else {
    __shared__ float Part[4][64];
    __shared__ float SaInv[64];
    __shared__ float RmS[64];
    __shared__ float Tile[64][65];
    const int l1 = len1[b], l2 = len2[b];
    const int j0 = s*64;
    if (tid < 64) RmS[tid] = __uint_as_float(RmU[b*SL + j0 + tid]);
    __syncthreads();
    {
      float sum = 0.f;
      for (int i=w; i<l1; i+=4)
        sum += __expf(fminf(eb[(size_t)i*SL + j0 + lane] - RmS[lane], 85.f));
      Part[w][lane] = sum;
    }
    __syncthreads();
    if (w==0){
      float s_ = Part[0][lane]+Part[1][lane]+Part[2][lane]+Part[3][lane];
      SaInv[lane] = (s_>0.f && (j0+lane)<l2) ? 1.f/s_ : 0.f;  // j>=l2: zero row (mask2 on alphas)
    }
    __syncthreads();
    // only Pa columns < round_up_32(l1) are ever read by the K-trimmed mlp2c
    const int kmax = (l1+31)&~31;
    const int nti = (kmax+63)>>6;
    for (int ti=0; ti<nti; ti++){
      const int i0 = ti*64;
      #pragma unroll 4
      for (int it=0; it<16; it++){
        int il = it*4 + w;
        int i = i0 + il;
        float v = eb[(size_t)i*SL + j0 + lane];
        float p = (i<l1) ? __expf(fminf(v - RmS[lane],85.f))*SaInv[lane] : 0.f;
        Tile[il][lane] = p;
      }
      __syncthreads();
      {
        int jl = tid>>2, q = tid&3;
        short8 o1, o2;
        #pragma unroll
        for (int u=0;u<8;u++){
          o1[u] = f2b(Tile[q*16+u][jl]);
          o2[u] = f2b(Tile[q*16+8+u][jl]);
        }
        short* dst = Pa + (size_t)b*SL*SL + (size_t)(j0+jl)*SL + i0 + q*16;
        *(short8*)dst = o1;
        *(short8*)(dst+8) = o2;
      }
      __syncthreads();
    }
  }
}

// ---------- ggemm: Gt[n][k], 512 threads / 8 waves (4x2), len-skip ----------
__global__ __launch_bounds__(512) void ggemm(
    const short* __restrict__ embb, const int* __restrict__ s1c, const int* __restrict__ s2c,
    const short* __restrict__ W1bt, short* __restrict__ G1t, short* __restrict__ G2t,
    const int* __restrict__ len1, const int* __restrict__ len2, int nbc)
{
  __shared__ __align__(16) short U[208*64];      // A-stage (first 64*PAD) / transpose buffer
  __shared__ __align__(16) short Bs[224*PAD];
  __shared__ int IdxS[64];
  const int tid=threadIdx.x, lane=tid&63, w=tid>>6, quad=lane>>4, ln=lane&15;
  const int wr=w>>1, wc=w&1;
  const int spp = 4*nbc;
  const int side = (blockIdx.x >= spp) ? 1 : 0;
  int lin = blockIdx.x - side*spp;
  int b, rb;
  if (nbc >= 8){ int sup=lin>>5, rem=lin&31; rb=rem>>3; b=sup*8+(rem&7); }
  else { b = lin>>2; rb = lin&3; }
  const int krow0 = rb*64;
  const int lenv = (side ? len2 : len1)[b];
  if (krow0 >= lenv) return;                     // skipped Gt columns are exactly those never read
  const int* idx = side ? s2c : s1c;
  short* Gt = (side ? G2t : G1t) + (size_t)b*GSTR;
  if (tid < 64) IdxS[tid] = idx[b*SL + krow0 + tid];
  __syncthreads();
  f32x4 acc[7];
  #pragma unroll
  for (int t=0;t<7;t++) acc[t]=(f32x4){0,0,0,0};
  const int r_ = tid>>2, c_ = tid&3;
  const int ar = r_;
  const size_t arow = (tid<256) ? (size_t)IdxS[ar]*EP : 0;

  short8 aR, bR0, bR1;
  if (tid<256) aR = *(const short8*)&embb[arow + c_*8];
  bR0 = *(const short8*)&W1bt[(size_t)r_*EP + c_*8];
  if (r_<96) bR1 = ldg_row(W1bt, 128+r_, EP, c_*8);

  for (int ks=0; ks<10; ks++){
    __syncthreads();
    if (tid<256) *(short8*)&U[ar*PAD + c_*8] = aR;
    *(short8*)&Bs[r_*PAD + c_*8] = bR0;
    if (r_<96) *(short8*)&Bs[(128+r_)*PAD + c_*8] = bR1;
    __syncthreads();
    if (ks < 9){
      const int k0 = (ks+1)*32;
      if (tid<256) aR = *(const short8*)&embb[arow + k0 + c_*8];
      bR0 = *(const short8*)&W1bt[(size_t)r_*EP + k0 + c_*8];
      if (r_<96) bR1 = ldg_row(W1bt, 128+r_, EP, k0 + c_*8);
    }
    short8 a = *(const short8*)&U[(wr*16+ln)*PAD + quad*8];
    #pragma unroll
    for (int tt=0; tt<7; tt++){
      short8 bb = *(const short8*)&Bs[(wc*112 + tt*16 + ln)*PAD + quad*8];
      acc[tt] = MFMA(a, bb, acc[tt]);
    }
  }
  __syncthreads();
  // epilogue: XOR-swizzled LDS transpose (octet o of row n stored at o^(n&7)), no bias/relu
  #pragma unroll
  for (int tt=0; tt<7; tt++){
    int n = (wc*7+tt)*16+ln;
    if (n < 208){
      #pragma unroll
      for (int r=0;r<4;r++){
        int kl = wr*16 + quad*4 + r;
        U[n*64 + ((kl>>3) ^ (n&7))*8 + (kl&7)] = f2b(acc[tt][r]);
      }
    }
  }
  __syncthreads();
  #pragma unroll
  for (int it=0; it<4; it++){
    int p = it*512+tid, n = p>>3, oct = p&7;
    if (n < 208){
      short8 v = *(const short8*)&U[n*64 + (oct^(n&7))*8];
      *(short8*)&Gt[(size_t)n*SL + krow0 + oct*8] = v;
    }
  }
}

// ---------- compare MLP: M=128, 512 threads / 8 waves (4x2); layer1 = emb@W1cTop + P@Gt (len-trimmed) ----------
__global__ __launch_bounds__(512) void mlp2c(
    const short* __restrict__ embb,
    const int* __restrict__ s1c, const int* __restrict__ s2c,
    const short* __restrict__ Pb, const short* __restrict__ Pa,
    const short* __restrict__ G2t, const short* __restrict__ G1t,
    const short* __restrict__ W1tT, const float* __restrict__ b1,
    const short* __restrict__ W2t, const float* __restrict__ b2,
    const int* __restrict__ len1, const int* __restrict__ len2,
    float* __restrict__ v1, float* __restrict__ v2, int nbc)
{
  __shared__ __align__(16) short U[128*TSP];     // A-stage (first 128*PAD) / layer-1 out union
  __shared__ __align__(16) short Bs[224*PAD];
  __shared__ int IdxS[128];
  const int tid=threadIdx.x, lane=tid&63, w=tid>>6, quad=lane>>4, ln=lane&15;
  const int wr=w>>1, wc=w&1;
  const int spp = 2*nbc;
  const int side = (blockIdx.x >= spp) ? 1 : 0;
  const int lin = blockIdx.x - side*spp;
  const int b = lin>>1, rb = lin&1;
  const int prow0 = rb*128;
  const int* idx = side ? s2c : s1c;
  const short* P = (side ? Pa : Pb) + (size_t)b*SL*SL;
  const short* Gt = (side ? G1t : G2t) + (size_t)b*GSTR;
  const int lenK = side ? len1[b] : len2[b];     // K-extent of the P@Gt phase
  const int lenM = side ? len2[b] : len1[b];     // row mask for the final sum
  const int NK = 10 + ((lenK+31)>>5);
  float* V = side ? v2 : v1;
  if (tid < 128) IdxS[tid] = idx[b*SL + prow0 + tid];
  __syncthreads();

  f32x4 acc0[7], acc1[7];
  #pragma unroll
  for (int t=0;t<7;t++){ acc0[t]=(f32x4){0,0,0,0}; acc1[t]=(f32x4){0,0,0,0}; }
  const int r_ = tid>>2, c_ = tid&3;      // r_: 0..127
  const size_t arow = (size_t)IdxS[r_]*EP;

  auto loadA = [&](int ks)->short8 {
    if (ks < 10) return *(const short8*)&embb[arow + ks*32 + c_*8];
    return *(const short8*)&P[(size_t)(prow0+r_)*SL + (ks-10)*32 + c_*8];
  };
  auto loadB = [&](int ks, int n)->short8 {
    if (n >= 208){ short8 z={0,0,0,0,0,0,0,0}; return z; }
    if (ks < 10) return *(const short8*)&W1tT[(size_t)n*EP + ks*32 + c_*8];
    return *(const short8*)&Gt[(size_t)n*SL + (ks-10)*32 + c_*8];
  };

  short8 aR, bR0, bR1;
  aR  = loadA(0);
  bR0 = loadB(0, r_);
  if (r_<96) bR1 = loadB(0, 128+r_);

  // ---- layer 1: NK fused K-steps (10 emb@W1cTop + ceil(lenK/32) P@Gt) ----
  for (int ks=0; ks<NK; ks++){
    __syncthreads();
    *(short8*)&U[r_*PAD + c_*8] = aR;
    *(short8*)&Bs[r_*PAD + c_*8] = bR0;
    if (r_<96) *(short8*)&Bs[(128+r_)*PAD + c_*8] = bR1;
    __syncthreads();
    if (ks+1 < NK){
      aR  = loadA(ks+1);
      bR0 = loadB(ks+1, r_);
      if (r_<96) bR1 = loadB(ks+1, 128+r_);
    }
    short8 a0 = *(const short8*)&U[(wr*32+ln)*PAD + quad*8];
    short8 a1 = *(const short8*)&U[(wr*32+16+ln)*PAD + quad*8];
    #pragma unroll
    for (int tt=0; tt<7; tt++){
      short8 bb = *(const short8*)&Bs[(wc*112 + tt*16 + ln)*PAD + quad*8];
      acc0[tt] = MFMA(a0, bb, acc0[tt]);
      acc1[tt] = MFMA(a1, bb, acc1[tt]);
    }
  }
  __syncthreads();
  // bias + relu -> U (stride TSP); cols >= HD written zero
  #pragma unroll
  for (int tt=0; tt<7; tt++){
    int col = (wc*7+tt)*16+ln;
    float bv = (col<HD) ? b1[col] : 0.f;
    #pragma unroll
    for (int r=0;r<4;r++){
      int rl = wr*32 + quad*4 + r;
      U[(rl   )*TSP + col] = f2b((col<HD) ? fmaxf(acc0[tt][r]+bv, 0.f) : 0.f);
      U[(rl+16)*TSP + col] = f2b((col<HD) ? fmaxf(acc1[tt][r]+bv, 0.f) : 0.f);
    }
    acc0[tt]=(f32x4){0,0,0,0}; acc1[tt]=(f32x4){0,0,0,0};
  }

  // ---- layer 2 (K=224, 7 steps) ----
  bR0 = *(const short8*)&W2t[(size_t)r_*HP + c_*8];
  if (r_<96) bR1 = ldg_row(W2t, 128+r_, HP, c_*8);
  for (int ks=0; ks<7; ks++){
    __syncthreads();   // first iter: covers epilogue U writes + last layer-1 Bs reads
    *(short8*)&Bs[r_*PAD + c_*8] = bR0;
    if (r_<96) *(short8*)&Bs[(128+r_)*PAD + c_*8] = bR1;
    __syncthreads();
    if (ks < 6){
      const int k0 = (ks+1)*32;
      bR0 = *(const short8*)&W2t[(size_t)r_*HP + k0 + c_*8];
      if (r_<96) bR1 = ldg_row(W2t, 128+r_, HP, k0 + c_*8);
    }
    short8 a0 = *(const short8*)&U[(wr*32+ln)*TSP + ks*32 + quad*8];
    short8 a1 = *(const short8*)&U[(wr*32+16+ln)*TSP + ks*32 + quad*8];
    #pragma unroll
    for (int tt=0; tt<7; tt++){
      short8 bb = *(const short8*)&Bs[(wc*112 + tt*16 + ln)*PAD + quad*8];
      acc0[tt] = MFMA(a0, bb, acc0[tt]);
      acc1[tt] = MFMA(a1, bb, acc1[tt]);
    }
  }
  // masked row-sum epilogue (32 rows per wave, quad-reduced)
  {
    const int posBase = prow0 + wr*32 + quad*4;
    #pragma unroll
    for (int tt=0; tt<7; tt++){
      int col = (wc*7+tt)*16+ln;
      float bv = (col<HD) ? b2[col] : 0.f;
      float s = 0.f;
      #pragma unroll
      for (int r=0;r<4;r++){
        float v0 = fmaxf(acc0[tt][r]+bv, 0.f); if (posBase    + r < lenM) s += v0;
        float v1_ = fmaxf(acc1[tt][r]+bv, 0.f); if (posBase+16 + r < lenM) s += v1_;
      }
      s += __shfl_xor(s,16);
      s += __shfl_xor(s,32);
      if (quad==0 && col<HD) atomicAdd(&V[b*HD+col], s);
    }
  }
}

// ---------- aggregate ----------
__global__ __launch_bounds__(256) void aggregate(
    const float* __restrict__ v1, const float* __restrict__ v2,
    const float* __restrict__ W1g, const float* __restrict__ b1g,
    const float* __restrict__ W2g, const float* __restrict__ b2g,
    float* __restrict__ out)
{
  __shared__ float z[2*HD];
  __shared__ float a[HD];
  const int b = blockIdx.x, t = threadIdx.x;
  if (t < HD){ z[t] = v1[b*HD+t]; z[HD+t] = v2[b*HD+t]; }
  __syncthreads();
  if (t < HD){
    float acc = b1g[t];
    for (int k=0;k<2*HD;k++) acc += z[k]*W1g[(size_t)k*HD+t];
    a[t] = fmaxf(acc, 0.f);
  }
  __syncthreads();
  if (t < 2){
    float acc = b2g[t];
    for (int k=0;k<HD;k++) acc += a[k]*W2g[k*2+t];
    out[b*2+t] = acc;
  }
}

extern "C" void kernel_launch(void* const* d_in, const int* in_sizes, int n_in,
                              void* d_out, int out_size, void* d_ws, size_t ws_size,
                              hipStream_t stream) {
  const float* emb = (const float*)d_in[0];
  const float* W1a = (const float*)d_in[1];  const float* b1a = (const float*)d_in[2];
  const float* W2a = (const float*)d_in[3];  const float* b2a = (const float*)d_in[4];
  const float* W1c = (const float*)d_in[5];  const float* b1c = (const float*)d_in[6];
  const float* W2c = (const float*)d_in[7];  const float* b2c = (const float*)d_in[8];
  const float* W1g = (const float*)d_in[9];  const float* b1g = (const float*)d_in[10];
  const float* W2g = (const float*)d_in[11]; const float* b2g = (const float*)d_in[12];
  const int* s1 = (const int*)d_in[13];
  const int* s2 = (const int*)d_in[14];
  const int* len1 = (const int*)d_in[15];
  const int* len2 = (const int*)d_in[16];
  float* out = (float*)d_out;
  char* W = (char*)d_ws;

  // ---- fixed region ----
  float* v1    = (float*)(W);                      // 409,600
  float* v2    = (float*)(W + 409600);             // 409,600
  short* embb  = (short*)(W + 819200);             // 32,000,000
  short* W1at  = (short*)(W + 32819200);           // 133,120
  short* W2at  = (short*)(W + 32952320);           //  93,184
  short* W1ctT = (short*)(W + 33045504);           // 133,120
  short* W1cbT = (short*)(W + 33178624);           // 133,120
  short* W2ct  = (short*)(W + 33311744);           //  93,184
  char*  C0    = W + 33404928;
  const size_t FIXED = 33404928ull;

  // ---- per-batch chunked region with lifetime overlays ----
  // R1 (262,144/batch): h1,h2 [mlp2 -> scores]  UNION  Pa,Pb [pwrite -> mlp2c]
  // R2 (262,144/batch): e     [scores -> pwrite] UNION  G1t,G2t [ggemm -> mlp2c]
  // RC (2,048/batch):   Rm, Cm
  const size_t PERB = 526336ull;
  int nbc = NB;
  while (nbc > 1 && FIXED + (size_t)nbc*PERB > ws_size) nbc >>= 1;
  const size_t nb = (size_t)nbc;
  char* R1 = C0;
  char* R2 = C0 + nb*262144;
  char* RC = C0 + nb*524288;
  short*    h1  = (short*)(R1);
  short*    h2  = (short*)(R1 + nb*114688);
  short*    Pa  = (short*)(R1);
  short*    Pb  = (short*)(R1 + nb*131072);
  float*    e   = (float*)(R2);
  short*    G1t = (short*)(R2);
  short*    G2t = (short*)(R2 + nb*106496);
  unsigned* Rm  = (unsigned*)(RC);
  unsigned* Cm  = (unsigned*)(RC + nb*1024);

  const dim3 blk(256);
  const dim3 blk512(512);
  hipMemsetAsync(v1, 0, 2ull*NB*HD*sizeof(float), stream);
  conv_emb<<<dim3((50000*EP+255)/256), blk, 0, stream>>>(emb, embb);
  convT_plain<<<dim3((208*EP+255)/256), blk, 0, stream>>>(W1a, W1at, ED, EP);
  convT_plain<<<dim3((208*HP+255)/256), blk, 0, stream>>>(W2a, W2at, HD, HP);
  convT_plain<<<dim3((208*EP+255)/256), blk, 0, stream>>>(W1c, W1ctT, ED, EP);
  convT_plain<<<dim3((208*EP+255)/256), blk, 0, stream>>>(W1c + (size_t)ED*HD, W1cbT, ED, EP);
  convT_plain<<<dim3((208*HP+255)/256), blk, 0, stream>>>(W2c, W2ct, HD, HP);

  const int chunks = NB / nbc;
  for (int c = 0; c < chunks; c++){
    const int b0 = c * nbc;
    const int* s1c = s1 + (size_t)b0*SL;
    const int* s2c = s2 + (size_t)b0*SL;
    const int* l1c = len1 + b0;
    const int* l2c = len2 + b0;

    hipMemsetAsync(Rm, 0, (size_t)nbc*SL*8, stream);   // Rm + Cm (contiguous), e>=0 so 0 is -inf
    mlp2<<<dim3(4*nbc), blk512, 0, stream>>>(embb, s1c, s2c, W1at, b1a, W2at, b2a, h1, h2);
    scores_gemm<<<dim3(4,4,nbc), blk, 0, stream>>>(h1, h2, e, Rm, Cm);
    pwrite_k<<<dim3(4,2,nbc), blk, 0, stream>>>(e, Rm, Cm, l1c, l2c, Pa, Pb);
    ggemm<<<dim3(8*nbc), blk512, 0, stream>>>(embb, s1c, s2c, W1cbT, G1t, G2t, l1c, l2c, nbc);
    mlp2c<<<dim3(4*nbc), blk512, 0, stream>>>(embb, s1c, s2c, Pb, Pa, G2t, G1t,
                                              W1ctT, b1c, W2ct, b2c, l1c, l2c,
                                              v1 + (size_t)b0*HD, v2 + (size_t)b0*HD, nbc);
  }
  aggregate<<<dim3(NB), blk, 0, stream>>>(v1, v2, W1g, b1g, W2g, b2g, out);
}

// Round 9
// 645.110 us; speedup vs baseline: 1.4603x; 1.0143x over previous
//
#include <hip/hip_runtime.h>
#include <hip/hip_bf16.h>

#define DEV static __device__ __forceinline__

typedef short short8 __attribute__((ext_vector_type(8)));
typedef short short4v __attribute__((ext_vector_type(4)));
typedef float f32x4 __attribute__((ext_vector_type(4)));

#define NB 512
#define SL 256
#define ED 300
#define HD 200
#define EP 320   // padded embed stride
#define HP 224   // padded hidden stride
#define TSP 232  // LDS layer-1 output tile stride
#define PAD 40
#define GSTR 53248   // per-(b,side) Gt size in shorts: 208*256

#define MFMA(a,b,c) __builtin_amdgcn_mfma_f32_16x16x32_bf16(a,b,c,0,0,0)

DEV short f2b(float f){ __hip_bfloat16 h = __float2bfloat16(f); short s; __builtin_memcpy(&s,&h,2); return s; }

// ---------- one-time conversions ----------
__global__ __launch_bounds__(256) void conv_emb(const float* __restrict__ src, short* __restrict__ dst){
  size_t g = (size_t)blockIdx.x*256 + threadIdx.x;
  if (g >= (size_t)50000*EP) return;
  int row = (int)(g/EP), k = (int)(g%EP);
  dst[g] = (k<ED) ? f2b(src[(size_t)row*ED + k]) : (short)0;
}
// Wt[n][k] (208 x KP) <- W[k][n] (Kreal x 200), zero padded
__global__ __launch_bounds__(256) void convT_plain(const float* __restrict__ W, short* __restrict__ Wt,
                                                   int Kreal, int KP){
  int g = blockIdx.x*256 + threadIdx.x;
  if (g >= 208*KP) return;
  int n = g/KP, k = g%KP;
  float v = (n<HD && k<Kreal) ? W[(size_t)k*HD + n] : 0.f;
  Wt[g] = f2b(v);
}

// ---------- merged: fused attend MLP (M=128) + ggemm (M=64), both 512 threads / 8 waves ----------
// 13 N-tiles (208 cols) instead of 14: tile 13 was pure zero-pad work. wc=0 waves own 7 tiles,
// wc=1 waves own 6; B staged 208 rows only; U/Out cols 208..223 zero-filled explicitly.
__global__ __launch_bounds__(512) void mlp2g(
    const short* __restrict__ embb,
    const int* __restrict__ idxA, const int* __restrict__ idxB,
    const short* __restrict__ W1t, const float* __restrict__ b1,
    const short* __restrict__ W2t, const float* __restrict__ b2,
    short* __restrict__ OutA, short* __restrict__ OutB,
    const short* __restrict__ W1bt, short* __restrict__ G1t, short* __restrict__ G2t,
    const int* __restrict__ len1, const int* __restrict__ len2, int nbc)
{
  __shared__ __align__(16) short U[128*TSP];     // mlp2: A-stage/L1-out union; ggemm: A-stage/transpose buf
  __shared__ __align__(16) short Bs[208*PAD];
  __shared__ int IdxS[128];
  const int tid=threadIdx.x, lane=tid&63, w=tid>>6, quad=lane>>4, ln=lane&15;
  const int wr=w>>1, wc=w&1;
  const int r_ = tid>>2, c_ = tid&3;
  const int NT = 7 - wc;                         // tiles per col-wave (7 or 6)

  if ((int)blockIdx.x < 4*nbc){
    // ================= mlp2: fused 2-layer attend MLP, M=128 =================
    const int half = 2*nbc;
    const int side = ((int)blockIdx.x >= half) ? 1 : 0;
    const int row0 = ((int)blockIdx.x - side*half)*128;
    const int* idx = side ? idxB : idxA;
    if (tid < 128) IdxS[tid] = idx[row0+tid];
    __syncthreads();

    f32x4 acc0[7], acc1[7];
    #pragma unroll
    for (int t=0;t<7;t++){ acc0[t]=(f32x4){0,0,0,0}; acc1[t]=(f32x4){0,0,0,0}; }
    const size_t arow = (size_t)IdxS[r_]*EP;

    short8 aR, bR0, bR1;
    aR  = *(const short8*)&embb[arow + c_*8];
    bR0 = *(const short8*)&W1t[(size_t)r_*EP + c_*8];
    if (r_<80) bR1 = *(const short8*)&W1t[(size_t)(128+r_)*EP + c_*8];

    // ---- layer 1 (K=320, 10 steps) ----
    for (int ks=0; ks<10; ks++){
      __syncthreads();
      *(short8*)&U[r_*PAD + c_*8] = aR;
      *(short8*)&Bs[r_*PAD + c_*8] = bR0;
      if (r_<80) *(short8*)&Bs[(128+r_)*PAD + c_*8] = bR1;
      __syncthreads();
      if (ks < 9){
        const int k0 = (ks+1)*32;
        aR  = *(const short8*)&embb[arow + k0 + c_*8];
        bR0 = *(const short8*)&W1t[(size_t)r_*EP + k0 + c_*8];
        if (r_<80) bR1 = *(const short8*)&W1t[(size_t)(128+r_)*EP + k0 + c_*8];
      }
      short8 a0 = *(const short8*)&U[(wr*32+ln)*PAD + quad*8];
      short8 a1 = *(const short8*)&U[(wr*32+16+ln)*PAD + quad*8];
      #pragma unroll
      for (int tt=0; tt<7; tt++){
        if (tt < NT){
          short8 bb = *(const short8*)&Bs[(wc*112 + tt*16 + ln)*PAD + quad*8];
          acc0[tt] = MFMA(a0, bb, acc0[tt]);
          acc1[tt] = MFMA(a1, bb, acc1[tt]);
        }
      }
    }
    __syncthreads();                     // all A-stage reads done before L1-out overwrites U
    // layer-1 epilogue -> U (stride TSP); cols >= HD written zero (covers 200..207)
    #pragma unroll
    for (int tt=0; tt<7; tt++){
      if (tt < NT){
        int col = (wc*7+tt)*16+ln;
        float bv = (col<HD) ? b1[col] : 0.f;
        #pragma unroll
        for (int r=0;r<4;r++){
          int rl = wr*32 + quad*4 + r;
          U[(rl   )*TSP + col] = f2b((col<HD) ? fmaxf(acc0[tt][r]+bv, 0.f) : 0.f);
          U[(rl+16)*TSP + col] = f2b((col<HD) ? fmaxf(acc1[tt][r]+bv, 0.f) : 0.f);
        }
      }
      acc0[tt]=(f32x4){0,0,0,0}; acc1[tt]=(f32x4){0,0,0,0};
    }
    // zero-fill cols 208..223 (layer-2 K tail reads them)
    { short4v z4 = {0,0,0,0};
      *(short4v*)&U[(tid>>2)*TSP + 208 + (tid&3)*4] = z4; }

    // ---- layer 2 (K=224, 7 steps) ----
    bR0 = *(const short8*)&W2t[(size_t)r_*HP + c_*8];
    if (r_<80) bR1 = *(const short8*)&W2t[(size_t)(128+r_)*HP + c_*8];
    for (int ks=0; ks<7; ks++){
      __syncthreads();   // first iter: covers epilogue U writes + last layer-1 Bs reads
      *(short8*)&Bs[r_*PAD + c_*8] = bR0;
      if (r_<80) *(short8*)&Bs[(128+r_)*PAD + c_*8] = bR1;
      __syncthreads();
      if (ks < 6){
        const int k0 = (ks+1)*32;
        bR0 = *(const short8*)&W2t[(size_t)r_*HP + k0 + c_*8];
        if (r_<80) bR1 = *(const short8*)&W2t[(size_t)(128+r_)*HP + k0 + c_*8];
      }
      short8 a0 = *(const short8*)&U[(wr*32+ln)*TSP + ks*32 + quad*8];
      short8 a1 = *(const short8*)&U[(wr*32+16+ln)*TSP + ks*32 + quad*8];
      #pragma unroll
      for (int tt=0; tt<7; tt++){
        if (tt < NT){
          short8 bb = *(const short8*)&Bs[(wc*112 + tt*16 + ln)*PAD + quad*8];
          acc0[tt] = MFMA(a0, bb, acc0[tt]);
          acc1[tt] = MFMA(a1, bb, acc1[tt]);
        }
      }
    }
    short* Out = side ? OutB : OutA;
    #pragma unroll
    for (int tt=0; tt<7; tt++){
      if (tt < NT){
        int col = (wc*7+tt)*16+ln;
        float bv = (col<HD) ? b2[col] : 0.f;
        #pragma unroll
        for (int r=0;r<4;r++){
          int rl = wr*32 + quad*4 + r;
          Out[(size_t)(row0+rl   )*HP + col] = f2b((col<HD) ? fmaxf(acc0[tt][r]+bv, 0.f) : 0.f);
          Out[(size_t)(row0+rl+16)*HP + col] = f2b((col<HD) ? fmaxf(acc1[tt][r]+bv, 0.f) : 0.f);
        }
      }
    }
    // zero-fill Out cols 208..223 (scores' K loop reads them)
    { short4v z4 = {0,0,0,0};
      *(short4v*)&Out[(size_t)(row0+(tid>>2))*HP + 208 + (tid&3)*4] = z4; }

  } else {
    // ================= ggemm: Gt[n][k] = emb[idx[k]] . W1cb[n], M=64, len-skip =================
    const int gb = (int)blockIdx.x - 4*nbc;
    const int spp = 4*nbc;
    const int side = (gb >= spp) ? 1 : 0;
    int lin = gb - side*spp;
    int b, rb;
    if (nbc >= 8){ int sup=lin>>5, rem=lin&31; rb=rem>>3; b=sup*8+(rem&7); }
    else { b = lin>>2; rb = lin&3; }
    const int krow0 = rb*64;
    const int lenv = (side ? len2 : len1)[b];
    if (krow0 >= lenv) return;                   // skipped Gt columns are exactly those never read
    const int* idx = side ? idxB : idxA;         // idxA=s1c, idxB=s2c
    short* Gt = (side ? G2t : G1t) + (size_t)b*GSTR;
    if (tid < 64) IdxS[tid] = idx[b*SL + krow0 + tid];
    __syncthreads();
    f32x4 acc[7];
    #pragma unroll
    for (int t=0;t<7;t++) acc[t]=(f32x4){0,0,0,0};
    const size_t arow = (tid<256) ? (size_t)IdxS[r_]*EP : 0;
    const int gwr = w>>1;                        // 4 row-groups of 16 (M=64)

    short8 aR, bR0, bR1;
    if (tid<256) aR = *(const short8*)&embb[arow + c_*8];
    bR0 = *(const short8*)&W1bt[(size_t)r_*EP + c_*8];
    if (r_<80) bR1 = *(const short8*)&W1bt[(size_t)(128+r_)*EP + c_*8];

    for (int ks=0; ks<10; ks++){
      __syncthreads();
      if (tid<256) *(short8*)&U[r_*PAD + c_*8] = aR;
      *(short8*)&Bs[r_*PAD + c_*8] = bR0;
      if (r_<80) *(short8*)&Bs[(128+r_)*PAD + c_*8] = bR1;
      __syncthreads();
      if (ks < 9){
        const int k0 = (ks+1)*32;
        if (tid<256) aR = *(const short8*)&embb[arow + k0 + c_*8];
        bR0 = *(const short8*)&W1bt[(size_t)r_*EP + k0 + c_*8];
        if (r_<80) bR1 = *(const short8*)&W1bt[(size_t)(128+r_)*EP + k0 + c_*8];
      }
      short8 a = *(const short8*)&U[(gwr*16+ln)*PAD + quad*8];
      #pragma unroll
      for (int tt=0; tt<7; tt++){
        if (tt < NT){
          short8 bb = *(const short8*)&Bs[(wc*112 + tt*16 + ln)*PAD + quad*8];
          acc[tt] = MFMA(a, bb, acc[tt]);
        }
      }
    }
    __syncthreads();
    // epilogue: XOR-swizzled LDS transpose (octet o of row n stored at o^(n&7)), no bias/relu
    #pragma unroll
    for (int tt=0; tt<7; tt++){
      if (tt < NT){
        int n = (wc*7+tt)*16+ln;                 // n <= 207
        #pragma unroll
        for (int r=0;r<4;r++){
          int kl = gwr*16 + quad*4 + r;
          U[n*64 + ((kl>>3) ^ (n&7))*8 + (kl&7)] = f2b(acc[tt][r]);
        }
      }
    }
    __syncthreads();
    #pragma unroll
    for (int it=0; it<4; it++){
      int p = it*512+tid, n = p>>3, oct = p&7;
      if (n < 208){
        short8 v = *(const short8*)&U[n*64 + (oct^(n&7))*8];
        *(short8*)&Gt[(size_t)n*SL + krow0 + oct*8] = v;
      }
    }
  }
}

// ---------- scores + fused row/col max (e >= 0 since h >= 0) ----------
__global__ __launch_bounds__(256) void scores_gemm(
    const short* __restrict__ h1, const short* __restrict__ h2, float* __restrict__ e,
    unsigned* __restrict__ RmU, unsigned* __restrict__ CmU)
{
  __shared__ __align__(16) short As[64*PAD];
  __shared__ __align__(16) short Bs[64*PAD];
  const int b = blockIdx.z;
  const int i0 = blockIdx.x*64, j0 = blockIdx.y*64;
  const int tid=threadIdx.x, lane=tid&63, w=tid>>6, quad=lane>>4, ln=lane&15;
  const int r_ = tid>>2, c_ = tid&3;
  f32x4 acc[4];
  #pragma unroll
  for (int t=0;t<4;t++) acc[t]=(f32x4){0.f,0.f,0.f,0.f};
  const short* Arow = &h1[((size_t)b*SL + i0 + r_)*HP + c_*8];
  const short* Brow = &h2[((size_t)b*SL + j0 + r_)*HP + c_*8];
  short8 aR = *(const short8*)Arow;
  short8 bR = *(const short8*)Brow;
  for (int ks=0; ks<7; ks++){
    __syncthreads();
    *(short8*)&As[r_*PAD + c_*8] = aR;
    *(short8*)&Bs[r_*PAD + c_*8] = bR;
    __syncthreads();
    if (ks < 6){
      aR = *(const short8*)(Arow + (ks+1)*32);
      bR = *(const short8*)(Brow + (ks+1)*32);
    }
    short8 a = *(const short8*)&As[(w*16+ln)*PAD + quad*8];
    #pragma unroll
    for (int t=0;t<4;t++){
      short8 bb = *(const short8*)&Bs[(t*16+ln)*PAD + quad*8];
      acc[t] = MFMA(a, bb, acc[t]);
    }
  }
  #pragma unroll
  for (int t=0;t<4;t++){
    int j = j0 + t*16 + ln;
    #pragma unroll
    for (int r=0;r<4;r++){
      int i = i0 + w*16 + quad*4 + r;
      e[(size_t)b*SL*SL + (size_t)i*SL + j] = acc[t][r];
    }
  }
  // row maxes (over j): reduce over ln within quad-group
  #pragma unroll
  for (int r=0;r<4;r++){
    float m = fmaxf(fmaxf(acc[0][r],acc[1][r]), fmaxf(acc[2][r],acc[3][r]));
    m=fmaxf(m,__shfl_xor(m,1)); m=fmaxf(m,__shfl_xor(m,2));
    m=fmaxf(m,__shfl_xor(m,4)); m=fmaxf(m,__shfl_xor(m,8));
    if (ln==0) atomicMax(&RmU[b*SL + i0 + w*16 + quad*4 + r], __float_as_uint(m));
  }
  // col maxes (over i): reduce over quad
  #pragma unroll
  for (int t=0;t<4;t++){
    float m = fmaxf(fmaxf(acc[t][0],acc[t][1]), fmaxf(acc[t][2],acc[t][3]));
    m=fmaxf(m,__shfl_xor(m,16)); m=fmaxf(m,__shfl_xor(m,32));
    if (quad==0) atomicMax(&CmU[b*SL + j0 + t*16 + ln], __float_as_uint(m));
  }
}

// ---------- P weights, normalized + masked + row-zeroed ----------
__global__ __launch_bounds__(256) void pwrite_k(
    const float* __restrict__ e, const unsigned* __restrict__ RmU, const unsigned* __restrict__ CmU,
    const int* __restrict__ len1, const int* __restrict__ len2,
    short* __restrict__ Pa, short* __restrict__ Pb)
{
  const int b = blockIdx.z, s = blockIdx.x, ori = blockIdx.y;
  const float* eb = e + (size_t)b*SL*SL;
  const int tid = threadIdx.x, lane = tid&63, w = tid>>6;
  if (ori == 0){
    const int l1 = len1[b], l2 = len2[b];
    if (s*64 >= l1) return;          // rows >= l1 are stale; masked out downstream
    for (int t=0;t<16;t++){
      int i = s*64 + w*16 + t;
      if (i >= l1) break;
      float cm = __uint_as_float(CmU[b*SL+i]);
      float4 v = ((const float4*)(eb + (size_t)i*SL))[lane];
      int c0 = lane*4;
      float e0 = (c0+0<l2) ? __expf(fminf(v.x-cm,85.f)) : 0.f;
      float e1 = (c0+1<l2) ? __expf(fminf(v.y-cm,85.f)) : 0.f;
      float e2 = (c0+2<l2) ? __expf(fminf(v.z-cm,85.f)) : 0.f;
      float e3 = (c0+3<l2) ? __expf(fminf(v.w-cm,85.f)) : 0.f;
      float ss = e0+e1+e2+e3;
      ss+=__shfl_xor(ss,1); ss+=__shfl_xor(ss,2); ss+=__shfl_xor(ss,4);
      ss+=__shfl_xor(ss,8); ss+=__shfl_xor(ss,16); ss+=__shfl_xor(ss,32);
      float inv = (ss>0.f) ? 1.f/ss : 0.f;
      short4v o; o[0]=f2b(e0*inv); o[1]=f2b(e1*inv); o[2]=f2b(e2*inv); o[3]=f2b(e3*inv);
      ((short4v*)(Pb + (size_t)b*SL*SL + (size_t)i*SL))[lane] = o;
    }
  } else {
    __shared__ float Part[4][64];
    __shared__ float SaInv[64];
    __shared__ float RmS[64];
    __shared__ float Tile[64][65];
    const int l1 = len1[b], l2 = len2[b];
    const int j0 = s*64;
    if (tid < 64) RmS[tid] = __uint_as_float(RmU[b*SL + j0 + tid]);
    __syncthreads();
    {
      float sum = 0.f;
      for (int i=w; i<l1; i+=4)
        sum += __expf(fminf(eb[(size_t)i*SL + j0 + lane] - RmS[lane], 85.f));
      Part[w][lane] = sum;
    }
    __syncthreads();
    if (w==0){
      float s_ = Part[0][lane]+Part[1][lane]+Part[2][lane]+Part[3][lane];
      SaInv[lane] = (s_>0.f && (j0+lane)<l2) ? 1.f/s_ : 0.f;  // j>=l2: zero row (mask2 on alphas)
    }
    __syncthreads();
    // only Pa columns < round_up_32(l1) are ever read by the K-trimmed mlp2c
    const int kmax = (l1+31)&~31;
    const int nti = (kmax+63)>>6;
    for (int ti=0; ti<nti; ti++){
      const int i0 = ti*64;
      #pragma unroll 4
      for (int it=0; it<16; it++){
        int il = it*4 + w;
        int i = i0 + il;
        float v = eb[(size_t)i*SL + j0 + lane];
        float p = (i<l1) ? __expf(fminf(v - RmS[lane],85.f))*SaInv[lane] : 0.f;
        Tile[il][lane] = p;
      }
      __syncthreads();
      {
        int jl = tid>>2, q = tid&3;
        short8 o1, o2;
        #pragma unroll
        for (int u=0;u<8;u++){
          o1[u] = f2b(Tile[q*16+u][jl]);
          o2[u] = f2b(Tile[q*16+8+u][jl]);
        }
        short* dst = Pa + (size_t)b*SL*SL + (size_t)(j0+jl)*SL + i0 + q*16;
        *(short8*)dst = o1;
        *(short8*)(dst+8) = o2;
      }
      __syncthreads();
    }
  }
}

// ---------- compare MLP: M=128, 512 threads / 8 waves (4x2); 13 N-tiles; len-trimmed P@Gt ----------
__global__ __launch_bounds__(512) void mlp2c(
    const short* __restrict__ embb,
    const int* __restrict__ s1c, const int* __restrict__ s2c,
    const short* __restrict__ Pb, const short* __restrict__ Pa,
    const short* __restrict__ G2t, const short* __restrict__ G1t,
    const short* __restrict__ W1tT, const float* __restrict__ b1,
    const short* __restrict__ W2t, const float* __restrict__ b2,
    const int* __restrict__ len1, const int* __restrict__ len2,
    float* __restrict__ v1, float* __restrict__ v2, int nbc)
{
  __shared__ __align__(16) short U[128*TSP];     // A-stage (first 128*PAD) / layer-1 out union
  __shared__ __align__(16) short Bs[208*PAD];
  __shared__ int IdxS[128];
  const int tid=threadIdx.x, lane=tid&63, w=tid>>6, quad=lane>>4, ln=lane&15;
  const int wr=w>>1, wc=w&1;
  const int NT = 7 - wc;
  const int spp = 2*nbc;
  const int side = ((int)blockIdx.x >= spp) ? 1 : 0;
  const int lin = (int)blockIdx.x - side*spp;
  const int b = lin>>1, rb = lin&1;
  const int prow0 = rb*128;
  const int* idx = side ? s2c : s1c;
  const short* P = (side ? Pa : Pb) + (size_t)b*SL*SL;
  const short* Gt = (side ? G1t : G2t) + (size_t)b*GSTR;
  const int lenK = side ? len1[b] : len2[b];     // K-extent of the P@Gt phase
  const int lenM = side ? len2[b] : len1[b];     // row mask for the final sum
  const int NK = 10 + ((lenK+31)>>5);
  float* V = side ? v2 : v1;
  if (tid < 128) IdxS[tid] = idx[b*SL + prow0 + tid];
  __syncthreads();

  f32x4 acc0[7], acc1[7];
  #pragma unroll
  for (int t=0;t<7;t++){ acc0[t]=(f32x4){0,0,0,0}; acc1[t]=(f32x4){0,0,0,0}; }
  const int r_ = tid>>2, c_ = tid&3;      // r_: 0..127
  const size_t arow = (size_t)IdxS[r_]*EP;

  auto loadA = [&](int ks)->short8 {
    if (ks < 10) return *(const short8*)&embb[arow + ks*32 + c_*8];
    return *(const short8*)&P[(size_t)(prow0+r_)*SL + (ks-10)*32 + c_*8];
  };
  auto loadB = [&](int ks, int n)->short8 {
    if (ks < 10) return *(const short8*)&W1tT[(size_t)n*EP + ks*32 + c_*8];
    return *(const short8*)&Gt[(size_t)n*SL + (ks-10)*32 + c_*8];
  };

  short8 aR, bR0, bR1;
  aR  = loadA(0);
  bR0 = loadB(0, r_);
  if (r_<80) bR1 = loadB(0, 128+r_);

  // ---- layer 1: NK fused K-steps (10 emb@W1cTop + ceil(lenK/32) P@Gt) ----
  for (int ks=0; ks<NK; ks++){
    __syncthreads();
    *(short8*)&U[r_*PAD + c_*8] = aR;
    *(short8*)&Bs[r_*PAD + c_*8] = bR0;
    if (r_<80) *(short8*)&Bs[(128+r_)*PAD + c_*8] = bR1;
    __syncthreads();
    if (ks+1 < NK){
      aR  = loadA(ks+1);
      bR0 = loadB(ks+1, r_);
      if (r_<80) bR1 = loadB(ks+1, 128+r_);
    }
    short8 a0 = *(const short8*)&U[(wr*32+ln)*PAD + quad*8];
    short8 a1 = *(const short8*)&U[(wr*32+16+ln)*PAD + quad*8];
    #pragma unroll
    for (int tt=0; tt<7; tt++){
      if (tt < NT){
        short8 bb = *(const short8*)&Bs[(wc*112 + tt*16 + ln)*PAD + quad*8];
        acc0[tt] = MFMA(a0, bb, acc0[tt]);
        acc1[tt] = MFMA(a1, bb, acc1[tt]);
      }
    }
  }
  __syncthreads();
  // bias + relu -> U (stride TSP); cols >= HD written zero (covers 200..207)
  #pragma unroll
  for (int tt=0; tt<7; tt++){
    if (tt < NT){
      int col = (wc*7+tt)*16+ln;
      float bv = (col<HD) ? b1[col] : 0.f;
      #pragma unroll
      for (int r=0;r<4;r++){
        int rl = wr*32 + quad*4 + r;
        U[(rl   )*TSP + col] = f2b((col<HD) ? fmaxf(acc0[tt][r]+bv, 0.f) : 0.f);
        U[(rl+16)*TSP + col] = f2b((col<HD) ? fmaxf(acc1[tt][r]+bv, 0.f) : 0.f);
      }
    }
    acc0[tt]=(f32x4){0,0,0,0}; acc1[tt]=(f32x4){0,0,0,0};
  }
  // zero-fill cols 208..223 (layer-2 K tail reads them)
  { short4v z4 = {0,0,0,0};
    *(short4v*)&U[(tid>>2)*TSP + 208 + (tid&3)*4] = z4; }

  // ---- layer 2 (K=224, 7 steps) ----
  bR0 = *(const short8*)&W2t[(size_t)r_*HP + c_*8];
  if (r_<80) bR1 = *(const short8*)&W2t[(size_t)(128+r_)*HP + c_*8];
  for (int ks=0; ks<7; ks++){
    __syncthreads();   // first iter: covers epilogue U writes + last layer-1 Bs reads
    *(short8*)&Bs[r_*PAD + c_*8] = bR0;
    if (r_<80) *(short8*)&Bs[(128+r_)*PAD + c_*8] = bR1;
    __syncthreads();
    if (ks < 6){
      const int k0 = (ks+1)*32;
      bR0 = *(const short8*)&W2t[(size_t)r_*HP + k0 + c_*8];
      if (r_<80) bR1 = *(const short8*)&W2t[(size_t)(128+r_)*HP + k0 + c_*8];
    }
    short8 a0 = *(const short8*)&U[(wr*32+ln)*TSP + ks*32 + quad*8];
    short8 a1 = *(const short8*)&U[(wr*32+16+ln)*TSP + ks*32 + quad*8];
    #pragma unroll
    for (int tt=0; tt<7; tt++){
      if (tt < NT){
        short8 bb = *(const short8*)&Bs[(wc*112 + tt*16 + ln)*PAD + quad*8];
        acc0[tt] = MFMA(a0, bb, acc0[tt]);
        acc1[tt] = MFMA(a1, bb, acc1[tt]);
      }
    }
  }
  // masked row-sum epilogue (32 rows per wave, quad-reduced)
  {
    const int posBase = prow0 + wr*32 + quad*4;
    #pragma unroll
    for (int tt=0; tt<7; tt++){
      if (tt < NT){
        int col = (wc*7+tt)*16+ln;
        float bv = (col<HD) ? b2[col] : 0.f;
        float s = 0.f;
        #pragma unroll
        for (int r=0;r<4;r++){
          float v0 = fmaxf(acc0[tt][r]+bv, 0.f); if (posBase    + r < lenM) s += v0;
          float v1_ = fmaxf(acc1[tt][r]+bv, 0.f); if (posBase+16 + r < lenM) s += v1_;
        }
        s += __shfl_xor(s,16);
        s += __shfl_xor(s,32);
        if (quad==0 && col<HD) atomicAdd(&V[b*HD+col], s);
      }
    }
  }
}

// ---------- aggregate ----------
__global__ __launch_bounds__(256) void aggregate(
    const float* __restrict__ v1, const float* __restrict__ v2,
    const float* __restrict__ W1g, const float* __restrict__ b1g,
    const float* __restrict__ W2g, const float* __restrict__ b2g,
    float* __restrict__ out)
{
  __shared__ float z[2*HD];
  __shared__ float a[HD];
  const int b = blockIdx.x, t = threadIdx.x;
  if (t < HD){ z[t] = v1[b*HD+t]; z[HD+t] = v2[b*HD+t]; }
  __syncthreads();
  if (t < HD){
    float acc = b1g[t];
    for (int k=0;k<2*HD;k++) acc += z[k]*W1g[(size_t)k*HD+t];
    a[t] = fmaxf(acc, 0.f);
  }
  __syncthreads();
  if (t < 2){
    float acc = b2g[t];
    for (int k=0;k<HD;k++) acc += a[k]*W2g[k*2+t];
    out[b*2+t] = acc;
  }
}

extern "C" void kernel_launch(void* const* d_in, const int* in_sizes, int n_in,
                              void* d_out, int out_size, void* d_ws, size_t ws_size,
                              hipStream_t stream) {
  const float* emb = (const float*)d_in[0];
  const float* W1a = (const float*)d_in[1];  const float* b1a = (const float*)d_in[2];
  const float* W2a = (const float*)d_in[3];  const float* b2a = (const float*)d_in[4];
  const float* W1c = (const float*)d_in[5];  const float* b1c = (const float*)d_in[6];
  const float* W2c = (const float*)d_in[7];  const float* b2c = (const float*)d_in[8];
  const float* W1g = (const float*)d_in[9];  const float* b1g = (const float*)d_in[10];
  const float* W2g = (const float*)d_in[11]; const float* b2g = (const float*)d_in[12];
  const int* s1 = (const int*)d_in[13];
  const int* s2 = (const int*)d_in[14];
  const int* len1 = (const int*)d_in[15];
  const int* len2 = (const int*)d_in[16];
  float* out = (float*)d_out;
  char* W = (char*)d_ws;

  // ---- fixed region ----
  float* v1    = (float*)(W);                      // 409,600
  float* v2    = (float*)(W + 409600);             // 409,600
  short* embb  = (short*)(W + 819200);             // 32,000,000
  short* W1at  = (short*)(W + 32819200);           // 133,120
  short* W2at  = (short*)(W + 32952320);           //  93,184
  short* W1ctT = (short*)(W + 33045504);           // 133,120
  short* W1cbT = (short*)(W + 33178624);           // 133,120
  short* W2ct  = (short*)(W + 33311744);           //  93,184
  char*  C0    = W + 33404928;
  const size_t FIXED = 33404928ull;

  // ---- per-batch chunked region with lifetime overlays ----
  // R1 (262,144/batch): h1,h2 [mlp2g -> scores]  UNION  Pa,Pb [pwrite -> mlp2c]
  // R2 (262,144/batch): e     [scores -> pwrite] UNION  G1t,G2t [mlp2g -> mlp2c]
  //   NOTE: G written by mlp2g while e not yet written (scores follows) -- G must not be
  //   clobbered by e. Order: mlp2g writes G; scores writes e OVER G region... WRONG? No:
  //   e is written by scores AFTER mlp2g, and G is read by mlp2c AFTER pwrite. e would
  //   clobber G. Therefore keep G in R2 only if e dies first -- it does not. Use:
  // R2 = e [scores->pwrite], R3 = G1t,G2t [mlp2g->mlp2c] (separate, 212,992/batch)
  const size_t PERB = 739328ull;   // 262144 + 262144 + 212992 + 2048
  int nbc = NB;
  while (nbc > 1 && FIXED + (size_t)nbc*PERB > ws_size) nbc >>= 1;
  const size_t nb = (size_t)nbc;
  char* R1 = C0;
  char* R2 = C0 + nb*262144;
  char* R3 = C0 + nb*524288;
  char* RC = C0 + nb*737280;
  short*    h1  = (short*)(R1);
  short*    h2  = (short*)(R1 + nb*114688);
  short*    Pa  = (short*)(R1);
  short*    Pb  = (short*)(R1 + nb*131072);
  float*    e   = (float*)(R2);
  short*    G1t = (short*)(R3);
  short*    G2t = (short*)(R3 + nb*106496);
  unsigned* Rm  = (unsigned*)(RC);
  unsigned* Cm  = (unsigned*)(RC + nb*1024);

  const dim3 blk(256);
  const dim3 blk512(512);
  hipMemsetAsync(v1, 0, 2ull*NB*HD*sizeof(float), stream);
  conv_emb<<<dim3((50000*EP+255)/256), blk, 0, stream>>>(emb, embb);
  convT_plain<<<dim3((208*EP+255)/256), blk, 0, stream>>>(W1a, W1at, ED, EP);
  convT_plain<<<dim3((208*HP+255)/256), blk, 0, stream>>>(W2a, W2at, HD, HP);
  convT_plain<<<dim3((208*EP+255)/256), blk, 0, stream>>>(W1c, W1ctT, ED, EP);
  convT_plain<<<dim3((208*EP+255)/256), blk, 0, stream>>>(W1c + (size_t)ED*HD, W1cbT, ED, EP);
  convT_plain<<<dim3((208*HP+255)/256), blk, 0, stream>>>(W2c, W2ct, HD, HP);

  const int chunks = NB / nbc;
  for (int c = 0; c < chunks; c++){
    const int b0 = c * nbc;
    const int* s1c = s1 + (size_t)b0*SL;
    const int* s2c = s2 + (size_t)b0*SL;
    const int* l1c = len1 + b0;
    const int* l2c = len2 + b0;

    hipMemsetAsync(Rm, 0, (size_t)nbc*SL*8, stream);   // Rm + Cm (contiguous), e>=0 so 0 is -inf
    mlp2g<<<dim3(12*nbc), blk512, 0, stream>>>(embb, s1c, s2c, W1at, b1a, W2at, b2a, h1, h2,
                                               W1cbT, G1t, G2t, l1c, l2c, nbc);
    scores_gemm<<<dim3(4,4,nbc), blk, 0, stream>>>(h1, h2, e, Rm, Cm);
    pwrite_k<<<dim3(4,2,nbc), blk, 0, stream>>>(e, Rm, Cm, l1c, l2c, Pa, Pb);
    mlp2c<<<dim3(4*nbc), blk512, 0, stream>>>(embb, s1c, s2c, Pb, Pa, G2t, G1t,
                                              W1ctT, b1c, W2ct, b2c, l1c, l2c,
                                              v1 + (size_t)b0*HD, v2 + (size_t)b0*HD, nbc);
  }
  aggregate<<<dim3(NB), blk, 0, stream>>>(v1, v2, W1g, b1g, W2g, b2g, out);
}